// Round 1
// baseline (792.128 us; speedup 1.0000x reference)
//
#include <hip/hip_runtime.h>

#define N_NODES 50000
#define N_EDGES 800000
#define NFEAT   128
#define HID     64
#define EPS_BN  1e-5f

// ---------------------------------------------------------------------------
// degree / dinv
// ---------------------------------------------------------------------------
__global__ void k_init_deg(float* __restrict__ deg) {
    int i = blockIdx.x * 256 + threadIdx.x;
    if (i < N_NODES) deg[i] = 1.0f;               // self-loop contributes 1
}

__global__ void k_edge_deg(const int* __restrict__ ei, float* __restrict__ deg) {
    int e = blockIdx.x * 256 + threadIdx.x;
    if (e < N_EDGES) atomicAdd(&deg[ei[N_EDGES + e]], 1.0f);   // dst row
}

__global__ void k_dinv(float* __restrict__ deg) {
    int i = blockIdx.x * 256 + threadIdx.x;
    if (i < N_NODES) deg[i] = rsqrtf(deg[i]);     // deg >= 1 always
}

// ---------------------------------------------------------------------------
// GEMM: out[row][col] = dinv[row] * sum_k Hin[row][k] * W[k][col]
// Hin optionally passed through per-column affine+relu (fused BN from prev layer)
// block = 256 threads, 64 rows per block, W and H tile staged in LDS.
// ---------------------------------------------------------------------------
template <int K, bool AFFINE>
__global__ __launch_bounds__(256) void k_gemm(const float* __restrict__ H,
                                              const float* __restrict__ W,
                                              const float* __restrict__ dinv,
                                              const float* __restrict__ affine,
                                              float* __restrict__ out) {
    __shared__ float Ws[K * HID];
    __shared__ float Hs[64 * K];
    const int tid  = threadIdx.x;
    const int row0 = blockIdx.x * 64;

    // stage W (K x 64)
    for (int i = tid * 4; i < K * HID; i += 256 * 4) {
        *(float4*)&Ws[i] = *(const float4*)&W[i];
    }
    // stage H tile (64 x K), with optional affine+relu on load
    for (int i = tid * 4; i < 64 * K; i += 256 * 4) {
        const int r   = i / K;
        const int c   = i % K;
        const int row = row0 + r;
        float4 v = make_float4(0.f, 0.f, 0.f, 0.f);
        if (row < N_NODES) v = *(const float4*)&H[(size_t)row * K + c];
        if (AFFINE) {
            v.x = fmaxf(0.f, fmaf(v.x, affine[c + 0], affine[HID + c + 0]));
            v.y = fmaxf(0.f, fmaf(v.y, affine[c + 1], affine[HID + c + 1]));
            v.z = fmaxf(0.f, fmaf(v.z, affine[c + 2], affine[HID + c + 2]));
            v.w = fmaxf(0.f, fmaf(v.w, affine[c + 3], affine[HID + c + 3]));
        }
        *(float4*)&Hs[i] = v;
    }
    __syncthreads();

    const int col = tid & 63;
    const int ty  = tid >> 6;
    for (int r = ty; r < 64; r += 4) {
        float acc = 0.f;
#pragma unroll 8
        for (int k = 0; k < K; ++k)
            acc = fmaf(Hs[r * K + k], Ws[k * HID + col], acc);
        const int row = row0 + r;
        if (row < N_NODES) out[(size_t)row * HID + col] = acc * dinv[row];
    }
}

// ---------------------------------------------------------------------------
// aggregation: agg initialized to ts (self-loop), then atomic adds over edges
// ---------------------------------------------------------------------------
__global__ __launch_bounds__(256) void k_copy_init(const float* __restrict__ src,
                                                   float* __restrict__ dst,
                                                   float* __restrict__ stats) {
    int i = blockIdx.x * 256 + threadIdx.x;
    int i4 = i * 4;
    if (i4 < N_NODES * HID) *(float4*)&dst[i4] = *(const float4*)&src[i4];
    if (i < 2 * HID) stats[i] = 0.f;
}

__global__ __launch_bounds__(256) void k_edge_agg(const float* __restrict__ ts,
                                                  const int* __restrict__ ei,
                                                  float* __restrict__ agg) {
    long long gid = (long long)blockIdx.x * 256 + threadIdx.x;
    int e = (int)(gid >> 6);
    if (e >= N_EDGES) return;
    int d = (int)(gid & 63);
    int s = ei[e];
    int t = ei[N_EDGES + e];
    atomicAdd(&agg[(size_t)t * HID + d], ts[(size_t)s * HID + d]);
}

// epilogue for BN layers: y = agg*dinv[row] + bias, in place; accumulate
// per-column sum and sumsq into stats[0:64], stats[64:128]
__global__ __launch_bounds__(256) void k_epi_bn(float* __restrict__ y,
                                                const float* __restrict__ dinv,
                                                const float* __restrict__ bias,
                                                float* __restrict__ stats) {
    const int tid = threadIdx.x;
    const int c   = tid & 63;
    const float b = bias[c];
    float s = 0.f, s2 = 0.f;
    const long long total  = (long long)N_NODES * HID;
    const long long stride = (long long)gridDim.x * 256;
    for (long long i = (long long)blockIdx.x * 256 + tid; i < total; i += stride) {
        const int row = (int)(i >> 6);
        float v = fmaf(y[i], dinv[row], b);
        y[i] = v;
        s  += v;
        s2 += v * v;
    }
    __shared__ float sm[512];
    sm[tid]       = s;
    sm[256 + tid] = s2;
    __syncthreads();
    if (tid < 64) {
        float t1 = sm[tid] + sm[tid + 64] + sm[tid + 128] + sm[tid + 192];
        float t2 = sm[256 + tid] + sm[256 + tid + 64] + sm[256 + tid + 128] + sm[256 + tid + 192];
        atomicAdd(&stats[tid],      t1);
        atomicAdd(&stats[64 + tid], t2);
    }
}

// BN finalize: affine[c] = scale, affine[64+c] = shift
__global__ void k_bn_final(const float* __restrict__ stats,
                           const float* __restrict__ g,
                           const float* __restrict__ be,
                           float* __restrict__ affine) {
    int c = threadIdx.x;
    if (c < HID) {
        float mu  = stats[c] * (1.0f / N_NODES);
        float var = stats[64 + c] * (1.0f / N_NODES) - mu * mu;
        var = fmaxf(var, 0.f);
        float sc = g[c] * rsqrtf(var + EPS_BN);
        affine[c]       = sc;
        affine[HID + c] = fmaf(-mu, sc, be[c]);
    }
}

// final epilogue: out[row] = dot(relu(agg*dinv + b2), fcW) + fcb
__global__ __launch_bounds__(256) void k_epi_final(const float* __restrict__ agg,
                                                   const float* __restrict__ dinv,
                                                   const float* __restrict__ b2,
                                                   const float* __restrict__ fcW,
                                                   const float* __restrict__ fcb,
                                                   float* __restrict__ out) {
    const int lane = threadIdx.x & 63;
    const int wid  = threadIdx.x >> 6;
    const float w  = fcW[lane];
    const float b  = b2[lane];
    const float fb = fcb[0];
    for (int row = blockIdx.x * 4 + wid; row < N_NODES; row += gridDim.x * 4) {
        float v = fmaxf(0.f, fmaf(agg[(size_t)row * HID + lane], dinv[row], b)) * w;
#pragma unroll
        for (int off = 32; off >= 1; off >>= 1) v += __shfl_xor(v, off, 64);
        if (lane == 0) out[row] = v + fb;
    }
}

// ---------------------------------------------------------------------------
extern "C" void kernel_launch(void* const* d_in, const int* in_sizes, int n_in,
                              void* d_out, int out_size, void* d_ws, size_t ws_size,
                              hipStream_t stream) {
    const float* x    = (const float*)d_in[0];
    const int*   ei   = (const int*)d_in[1];
    const float* W0   = (const float*)d_in[2];
    const float* b0   = (const float*)d_in[3];
    const float* W1   = (const float*)d_in[4];
    const float* b1   = (const float*)d_in[5];
    const float* W2   = (const float*)d_in[6];
    const float* b2   = (const float*)d_in[7];
    const float* g0   = (const float*)d_in[8];
    const float* be0  = (const float*)d_in[9];
    const float* g1   = (const float*)d_in[10];
    const float* be1  = (const float*)d_in[11];
    const float* fcW  = (const float*)d_in[12];
    const float* fcb  = (const float*)d_in[13];
    float* out        = (float*)d_out;

    // workspace layout (256B aligned)
    char* ws = (char*)d_ws;
    size_t off = 0;
    auto alloc = [&](size_t bytes) {
        size_t o = off;
        off += (bytes + 255) & ~(size_t)255;
        return (float*)(ws + o);
    };
    float* dinv   = alloc((size_t)N_NODES * 4);          // deg -> dinv in place
    float* bufA   = alloc((size_t)N_NODES * HID * 4);    // ts
    float* bufB   = alloc((size_t)N_NODES * HID * 4);    // agg / y
    float* stats  = alloc(2 * HID * 4);
    float* affine = alloc(2 * HID * 4);

    const int gN      = (N_NODES + 255) / 256;
    const int gE      = (N_EDGES + 255) / 256;
    const int gGemm   = (N_NODES + 63) / 64;
    const int gCopy   = (N_NODES * HID / 4 + 255) / 256;
    const long long eaTot = (long long)N_EDGES * HID;
    const int gEA     = (int)((eaTot + 255) / 256);

    // degree / dinv (once)
    k_init_deg<<<gN, 256, 0, stream>>>(dinv);
    k_edge_deg<<<gE, 256, 0, stream>>>(ei, dinv);
    k_dinv<<<gN, 256, 0, stream>>>(dinv);

    // ---- layer 0: x[50000,128] @ W0 -> agg -> BN stats
    k_gemm<NFEAT, false><<<gGemm, 256, 0, stream>>>(x, W0, dinv, nullptr, bufA);
    k_copy_init<<<gCopy, 256, 0, stream>>>(bufA, bufB, stats);
    k_edge_agg<<<gEA, 256, 0, stream>>>(bufA, ei, bufB);
    k_epi_bn<<<1024, 256, 0, stream>>>(bufB, dinv, b0, stats);
    k_bn_final<<<1, 64, 0, stream>>>(stats, g0, be0, affine);

    // ---- layer 1: relu(BN(y0)) @ W1 -> agg -> BN stats
    k_gemm<HID, true><<<gGemm, 256, 0, stream>>>(bufB, W1, dinv, affine, bufA);
    k_copy_init<<<gCopy, 256, 0, stream>>>(bufA, bufB, stats);
    k_edge_agg<<<gEA, 256, 0, stream>>>(bufA, ei, bufB);
    k_epi_bn<<<1024, 256, 0, stream>>>(bufB, dinv, b1, stats);
    k_bn_final<<<1, 64, 0, stream>>>(stats, g1, be1, affine);

    // ---- layer 2: relu(BN(y1)) @ W2 -> agg -> relu -> fc
    k_gemm<HID, true><<<gGemm, 256, 0, stream>>>(bufB, W2, dinv, affine, bufA);
    k_copy_init<<<gCopy, 256, 0, stream>>>(bufA, bufB, stats);
    k_edge_agg<<<gEA, 256, 0, stream>>>(bufA, ei, bufB);
    k_epi_final<<<12500, 256, 0, stream>>>(bufB, dinv, b2, fcW, fcb, out);
}

// Round 2
// 519.656 us; speedup vs baseline: 1.5243x; 1.5243x over previous
//
#include <hip/hip_runtime.h>

#define N_NODES 50000
#define N_EDGES 800000
#define NFEAT   128
#define HID     64
#define EPS_BN  1e-5f

// ---------------------------------------------------------------------------
// zero scratch: counts, fill, stats0, stats1
// ---------------------------------------------------------------------------
__global__ void k_zero(int* __restrict__ counts, int* __restrict__ fill,
                       float* __restrict__ st0, float* __restrict__ st1) {
    int i = blockIdx.x * 256 + threadIdx.x;
    if (i < N_NODES) { counts[i] = 0; fill[i] = 0; }
    if (i < 2 * HID) { st0[i] = 0.f; st1[i] = 0.f; }
}

__global__ void k_count(const int* __restrict__ ei, int* __restrict__ counts) {
    int e = blockIdx.x * 256 + threadIdx.x;
    if (e < N_EDGES) atomicAdd(&counts[ei[N_EDGES + e]], 1);
}

__global__ void k_dinv(const int* __restrict__ counts, float* __restrict__ dinv) {
    int i = blockIdx.x * 256 + threadIdx.x;
    if (i < N_NODES) dinv[i] = rsqrtf((float)(counts[i] + 1));  // +1 self loop
}

// one-block exclusive scan of counts -> rowptr (50001 entries)
__global__ __launch_bounds__(1024) void k_scan(const int* __restrict__ counts,
                                               int* __restrict__ rowptr) {
    __shared__ int part[1024];
    const int CH  = (N_NODES + 1023) / 1024;
    const int tid = threadIdx.x;
    int begin = tid * CH; if (begin > N_NODES) begin = N_NODES;
    int end   = begin + CH; if (end > N_NODES) end = N_NODES;
    int s = 0;
    for (int i = begin; i < end; ++i) s += counts[i];
    part[tid] = s;
    __syncthreads();
    for (int off = 1; off < 1024; off <<= 1) {
        int v = (tid >= off) ? part[tid - off] : 0;
        __syncthreads();
        part[tid] += v;
        __syncthreads();
    }
    int run = part[tid] - s;   // exclusive prefix
    for (int i = begin; i < end; ++i) { rowptr[i] = run; run += counts[i]; }
    if (tid == 1023) rowptr[N_NODES] = run;
}

__global__ void k_scatter(const int* __restrict__ ei, const int* __restrict__ rowptr,
                          int* __restrict__ fill, int* __restrict__ col) {
    int e = blockIdx.x * 256 + threadIdx.x;
    if (e >= N_EDGES) return;
    int s = ei[e];
    int t = ei[N_EDGES + e];
    int pos = rowptr[t] + atomicAdd(&fill[t], 1);
    col[pos] = s;
}

// ---------------------------------------------------------------------------
// GEMM: out[row][col] = dinv[row] * sum_k Hin[row][k] * W[k][col]
// Hin optionally passed through per-column affine+relu (fused BN from prev layer)
// ---------------------------------------------------------------------------
template <int K, bool AFFINE>
__global__ __launch_bounds__(256) void k_gemm(const float* __restrict__ H,
                                              const float* __restrict__ W,
                                              const float* __restrict__ dinv,
                                              const float* __restrict__ affine,
                                              float* __restrict__ out) {
    __shared__ float Ws[K * HID];
    __shared__ float Hs[64 * K];
    const int tid  = threadIdx.x;
    const int row0 = blockIdx.x * 64;

    for (int i = tid * 4; i < K * HID; i += 256 * 4)
        *(float4*)&Ws[i] = *(const float4*)&W[i];

    for (int i = tid * 4; i < 64 * K; i += 256 * 4) {
        const int r   = i / K;
        const int c   = i % K;
        const int row = row0 + r;
        float4 v = make_float4(0.f, 0.f, 0.f, 0.f);
        if (row < N_NODES) v = *(const float4*)&H[(size_t)row * K + c];
        if (AFFINE) {
            v.x = fmaxf(0.f, fmaf(v.x, affine[c + 0], affine[HID + c + 0]));
            v.y = fmaxf(0.f, fmaf(v.y, affine[c + 1], affine[HID + c + 1]));
            v.z = fmaxf(0.f, fmaf(v.z, affine[c + 2], affine[HID + c + 2]));
            v.w = fmaxf(0.f, fmaf(v.w, affine[c + 3], affine[HID + c + 3]));
        }
        *(float4*)&Hs[i] = v;
    }
    __syncthreads();

    const int col = tid & 63;
    const int ty  = tid >> 6;
    for (int r = ty; r < 64; r += 4) {
        float acc = 0.f;
#pragma unroll 8
        for (int k = 0; k < K; ++k)
            acc = fmaf(Hs[r * K + k], Ws[k * HID + col], acc);
        const int row = row0 + r;
        if (row < N_NODES) out[(size_t)row * HID + col] = acc * dinv[row];
    }
}

// ---------------------------------------------------------------------------
// CSR gather + epilogue (BN layers): one wave per node, lane = feature.
// y = (ts[v] + sum_{u in nbr(v)} ts[u]) * dinv[v] + bias; accumulate BN stats.
// ---------------------------------------------------------------------------
__global__ __launch_bounds__(256) void k_gather_bn(const float* __restrict__ ts,
                                                   const int* __restrict__ rowptr,
                                                   const int* __restrict__ col,
                                                   const float* __restrict__ dinv,
                                                   const float* __restrict__ bias,
                                                   float* __restrict__ y,
                                                   float* __restrict__ stats) {
    const int tid  = threadIdx.x;
    const int lane = tid & 63;
    const int w    = tid >> 6;
    const float b  = bias[lane];
    float s = 0.f, s2 = 0.f;
    for (int node = blockIdx.x * 4 + w; node < N_NODES; node += gridDim.x * 4) {
        float acc = ts[(size_t)node * HID + lane];     // self loop
        const int e0 = rowptr[node];
        const int e1 = rowptr[node + 1];
        int e = e0;
        for (; e + 1 < e1; e += 2) {
            const int u0 = col[e];
            const int u1 = col[e + 1];
            const float a0 = ts[(size_t)u0 * HID + lane];
            const float a1 = ts[(size_t)u1 * HID + lane];
            acc += a0;
            acc += a1;
        }
        if (e < e1) acc += ts[(size_t)col[e] * HID + lane];
        const float v = fmaf(acc, dinv[node], b);
        y[(size_t)node * HID + lane] = v;
        s  += v;
        s2 += v * v;
    }
    __shared__ float sm[512];
    sm[tid]       = s;
    sm[256 + tid] = s2;
    __syncthreads();
    if (tid < 64) {
        float t1 = sm[tid] + sm[tid + 64] + sm[tid + 128] + sm[tid + 192];
        float t2 = sm[256 + tid] + sm[256 + tid + 64] + sm[256 + tid + 128] + sm[256 + tid + 192];
        atomicAdd(&stats[tid],      t1);
        atomicAdd(&stats[64 + tid], t2);
    }
}

// BN finalize: affine[c] = scale, affine[64+c] = shift
__global__ void k_bn_final(const float* __restrict__ stats,
                           const float* __restrict__ g,
                           const float* __restrict__ be,
                           float* __restrict__ affine) {
    int c = threadIdx.x;
    if (c < HID) {
        float mu  = stats[c] * (1.0f / N_NODES);
        float var = stats[64 + c] * (1.0f / N_NODES) - mu * mu;
        var = fmaxf(var, 0.f);
        float sc = g[c] * rsqrtf(var + EPS_BN);
        affine[c]       = sc;
        affine[HID + c] = fmaf(-mu, sc, be[c]);
    }
}

// ---------------------------------------------------------------------------
// CSR gather + final epilogue: out[v] = dot(relu(agg*dinv + b2), fcW) + fcb
// ---------------------------------------------------------------------------
__global__ __launch_bounds__(256) void k_gather_final(const float* __restrict__ ts,
                                                      const int* __restrict__ rowptr,
                                                      const int* __restrict__ col,
                                                      const float* __restrict__ dinv,
                                                      const float* __restrict__ b2,
                                                      const float* __restrict__ fcW,
                                                      const float* __restrict__ fcb,
                                                      float* __restrict__ out) {
    const int tid  = threadIdx.x;
    const int lane = tid & 63;
    const int w    = tid >> 6;
    const float fw = fcW[lane];
    const float b  = b2[lane];
    const float fb = fcb[0];
    for (int node = blockIdx.x * 4 + w; node < N_NODES; node += gridDim.x * 4) {
        float acc = ts[(size_t)node * HID + lane];
        const int e0 = rowptr[node];
        const int e1 = rowptr[node + 1];
        int e = e0;
        for (; e + 1 < e1; e += 2) {
            const int u0 = col[e];
            const int u1 = col[e + 1];
            const float a0 = ts[(size_t)u0 * HID + lane];
            const float a1 = ts[(size_t)u1 * HID + lane];
            acc += a0;
            acc += a1;
        }
        if (e < e1) acc += ts[(size_t)col[e] * HID + lane];
        float v = fmaxf(0.f, fmaf(acc, dinv[node], b)) * fw;
#pragma unroll
        for (int off = 32; off >= 1; off >>= 1) v += __shfl_xor(v, off, 64);
        if (lane == 0) out[node] = v + fb;
    }
}

// ---------------------------------------------------------------------------
extern "C" void kernel_launch(void* const* d_in, const int* in_sizes, int n_in,
                              void* d_out, int out_size, void* d_ws, size_t ws_size,
                              hipStream_t stream) {
    const float* x    = (const float*)d_in[0];
    const int*   ei   = (const int*)d_in[1];
    const float* W0   = (const float*)d_in[2];
    const float* b0   = (const float*)d_in[3];
    const float* W1   = (const float*)d_in[4];
    const float* b1   = (const float*)d_in[5];
    const float* W2   = (const float*)d_in[6];
    const float* b2   = (const float*)d_in[7];
    const float* g0   = (const float*)d_in[8];
    const float* be0  = (const float*)d_in[9];
    const float* g1   = (const float*)d_in[10];
    const float* be1  = (const float*)d_in[11];
    const float* fcW  = (const float*)d_in[12];
    const float* fcb  = (const float*)d_in[13];
    float* out        = (float*)d_out;

    char* ws = (char*)d_ws;
    size_t off = 0;
    auto alloc = [&](size_t bytes) -> void* {
        size_t o = off;
        off += (bytes + 255) & ~(size_t)255;
        return (void*)(ws + o);
    };
    float* bufA    = (float*)alloc((size_t)N_NODES * HID * 4);   // ts
    float* bufB    = (float*)alloc((size_t)N_NODES * HID * 4);   // y
    int*   col     = (int*)  alloc((size_t)N_EDGES * 4);
    float* dinv    = (float*)alloc((size_t)N_NODES * 4);
    int*   counts  = (int*)  alloc((size_t)N_NODES * 4);
    int*   fill    = (int*)  alloc((size_t)N_NODES * 4);
    int*   rowptr  = (int*)  alloc((size_t)(N_NODES + 1) * 4);
    float* stats0  = (float*)alloc(2 * HID * 4);
    float* stats1  = (float*)alloc(2 * HID * 4);
    float* affine0 = (float*)alloc(2 * HID * 4);
    float* affine1 = (float*)alloc(2 * HID * 4);

    const int gN    = (N_NODES + 255) / 256;
    const int gE    = (N_EDGES + 255) / 256;
    const int gGemm = (N_NODES + 63) / 64;
    const int gGath = 2048;

    // CSR build + dinv
    k_zero<<<gN, 256, 0, stream>>>(counts, fill, stats0, stats1);
    k_count<<<gE, 256, 0, stream>>>(ei, counts);
    k_dinv<<<gN, 256, 0, stream>>>(counts, dinv);
    k_scan<<<1, 1024, 0, stream>>>(counts, rowptr);
    k_scatter<<<gE, 256, 0, stream>>>(ei, rowptr, fill, col);

    // ---- layer 0
    k_gemm<NFEAT, false><<<gGemm, 256, 0, stream>>>(x, W0, dinv, nullptr, bufA);
    k_gather_bn<<<gGath, 256, 0, stream>>>(bufA, rowptr, col, dinv, b0, bufB, stats0);
    k_bn_final<<<1, 64, 0, stream>>>(stats0, g0, be0, affine0);

    // ---- layer 1
    k_gemm<HID, true><<<gGemm, 256, 0, stream>>>(bufB, W1, dinv, affine0, bufA);
    k_gather_bn<<<gGath, 256, 0, stream>>>(bufA, rowptr, col, dinv, b1, bufB, stats1);
    k_bn_final<<<1, 64, 0, stream>>>(stats1, g1, be1, affine1);

    // ---- layer 2
    k_gemm<HID, true><<<gGemm, 256, 0, stream>>>(bufB, W2, dinv, affine1, bufA);
    k_gather_final<<<gGath, 256, 0, stream>>>(bufA, rowptr, col, dinv, b2, fcW, fcb, out);
}

// Round 3
// 435.009 us; speedup vs baseline: 1.8209x; 1.1946x over previous
//
#include <hip/hip_runtime.h>

#define N_NODES 50000
#define N_EDGES 800000
#define NFEAT   128
#define HID     64
#define EPS_BN  1e-5f

// bf16 <-> f32 helpers (RNE on store)
__device__ __forceinline__ float b2f(unsigned short u) {
    union { unsigned int i; float f; } c;
    c.i = ((unsigned int)u) << 16;
    return c.f;
}
__device__ __forceinline__ unsigned short f2b(float f) {
    union { float f; unsigned int i; } c;
    c.f = f;
    unsigned int i = c.i;
    return (unsigned short)((i + 0x7fffu + ((i >> 16) & 1u)) >> 16);
}

// ---------------------------------------------------------------------------
// CSR build
// ---------------------------------------------------------------------------
__global__ void k_zero(int* __restrict__ counts, int* __restrict__ fill,
                       float* __restrict__ st0, float* __restrict__ st1) {
    int i = blockIdx.x * 256 + threadIdx.x;
    if (i < N_NODES) { counts[i] = 0; fill[i] = 0; }
    if (i < 2 * HID) { st0[i] = 0.f; st1[i] = 0.f; }
}

__global__ void k_count(const int* __restrict__ ei, int* __restrict__ counts) {
    int e = blockIdx.x * 256 + threadIdx.x;
    if (e < N_EDGES) atomicAdd(&counts[ei[N_EDGES + e]], 1);
}

__global__ void k_dinv(const int* __restrict__ counts, float* __restrict__ dinv) {
    int i = blockIdx.x * 256 + threadIdx.x;
    if (i < N_NODES) dinv[i] = rsqrtf((float)(counts[i] + 1));  // +1 self loop
}

__global__ __launch_bounds__(1024) void k_scan(const int* __restrict__ counts,
                                               int* __restrict__ rowptr) {
    __shared__ int part[1024];
    const int CH  = (N_NODES + 1023) / 1024;
    const int tid = threadIdx.x;
    int begin = tid * CH; if (begin > N_NODES) begin = N_NODES;
    int end   = begin + CH; if (end > N_NODES) end = N_NODES;
    int s = 0;
    for (int i = begin; i < end; ++i) s += counts[i];
    part[tid] = s;
    __syncthreads();
    for (int off = 1; off < 1024; off <<= 1) {
        int v = (tid >= off) ? part[tid - off] : 0;
        __syncthreads();
        part[tid] += v;
        __syncthreads();
    }
    int run = part[tid] - s;
    for (int i = begin; i < end; ++i) { rowptr[i] = run; run += counts[i]; }
    if (tid == 1023) rowptr[N_NODES] = run;
}

__global__ void k_scatter(const int* __restrict__ ei, const int* __restrict__ rowptr,
                          int* __restrict__ fill, int* __restrict__ col) {
    int e = blockIdx.x * 256 + threadIdx.x;
    if (e >= N_EDGES) return;
    int s = ei[e];
    int t = ei[N_EDGES + e];
    int pos = rowptr[t] + atomicAdd(&fill[t], 1);
    col[pos] = s;
}

// ---------------------------------------------------------------------------
// GEMM: ts[row][col] = bf16( dinv[row] * sum_k Hin[row][k] * W[k][col] )
// thread owns 2 adjacent cols -> ushort2 stores.
// ---------------------------------------------------------------------------
template <int K, bool AFFINE>
__global__ __launch_bounds__(256) void k_gemm(const float* __restrict__ H,
                                              const float* __restrict__ W,
                                              const float* __restrict__ dinv,
                                              const float* __restrict__ affine,
                                              unsigned short* __restrict__ ts) {
    __shared__ float Ws[K * HID];
    __shared__ float Hs[64 * K];
    const int tid  = threadIdx.x;
    const int row0 = blockIdx.x * 64;

    for (int i = tid * 4; i < K * HID; i += 256 * 4)
        *(float4*)&Ws[i] = *(const float4*)&W[i];

    for (int i = tid * 4; i < 64 * K; i += 256 * 4) {
        const int r   = i / K;
        const int c   = i % K;
        const int row = row0 + r;
        float4 v = make_float4(0.f, 0.f, 0.f, 0.f);
        if (row < N_NODES) v = *(const float4*)&H[(size_t)row * K + c];
        if (AFFINE) {
            v.x = fmaxf(0.f, fmaf(v.x, affine[c + 0], affine[HID + c + 0]));
            v.y = fmaxf(0.f, fmaf(v.y, affine[c + 1], affine[HID + c + 1]));
            v.z = fmaxf(0.f, fmaf(v.z, affine[c + 2], affine[HID + c + 2]));
            v.w = fmaxf(0.f, fmaf(v.w, affine[c + 3], affine[HID + c + 3]));
        }
        *(float4*)&Hs[i] = v;
    }
    __syncthreads();

    const int col2 = (tid & 31) * 2;
    const int ty   = tid >> 5;            // 0..7
    for (int r = ty; r < 64; r += 8) {
        float a0 = 0.f, a1 = 0.f;
#pragma unroll 8
        for (int k = 0; k < K; ++k) {
            const float h = Hs[r * K + k];
            a0 = fmaf(h, Ws[k * HID + col2],     a0);
            a1 = fmaf(h, Ws[k * HID + col2 + 1], a1);
        }
        const int row = row0 + r;
        if (row < N_NODES) {
            const float d = dinv[row];
            ushort2 o;
            o.x = f2b(a0 * d);
            o.y = f2b(a1 * d);
            *(ushort2*)&ts[(size_t)row * HID + col2] = o;
        }
    }
}

// ---------------------------------------------------------------------------
// CSR gather (bf16 ts) + BN epilogue. 2 nodes per wave: half-wave per node,
// lane owns features {2sl, 2sl+1}. Edge loop unrolled x4 (8 gathers in flight).
// ---------------------------------------------------------------------------
__global__ __launch_bounds__(256) void k_gather_bn(const ushort2* __restrict__ ts2,
                                                   const int* __restrict__ rowptr,
                                                   const int* __restrict__ col,
                                                   const float* __restrict__ dinv,
                                                   const float* __restrict__ bias,
                                                   float* __restrict__ y,
                                                   float* __restrict__ stats) {
    const int tid  = threadIdx.x;
    const int w    = tid >> 6;
    const int lane = tid & 63;
    const int half = lane >> 5;
    const int sl   = lane & 31;
    const float2 bv = ((const float2*)bias)[sl];
    float sA = 0.f, s2A = 0.f, sB = 0.f, s2B = 0.f;

    for (int pair = blockIdx.x * 4 + w; pair < N_NODES / 2; pair += gridDim.x * 4) {
        const int node = pair * 2 + half;
        const ushort2 self = ts2[(size_t)node * 32 + sl];
        float acc0 = b2f(self.x), acc1 = b2f(self.y);
        const int e1 = rowptr[node + 1];
        int e = rowptr[node];
        for (; e + 3 < e1; e += 4) {
            const int u0 = col[e], u1 = col[e + 1], u2 = col[e + 2], u3 = col[e + 3];
            const ushort2 a0 = ts2[(size_t)u0 * 32 + sl];
            const ushort2 a1 = ts2[(size_t)u1 * 32 + sl];
            const ushort2 a2 = ts2[(size_t)u2 * 32 + sl];
            const ushort2 a3 = ts2[(size_t)u3 * 32 + sl];
            acc0 += b2f(a0.x) + b2f(a1.x) + b2f(a2.x) + b2f(a3.x);
            acc1 += b2f(a0.y) + b2f(a1.y) + b2f(a2.y) + b2f(a3.y);
        }
        for (; e < e1; ++e) {
            const ushort2 a = ts2[(size_t)col[e] * 32 + sl];
            acc0 += b2f(a.x);
            acc1 += b2f(a.y);
        }
        const float d  = dinv[node];
        const float v0 = fmaf(acc0, d, bv.x);
        const float v1 = fmaf(acc1, d, bv.y);
        ((float2*)y)[(size_t)node * 32 + sl] = make_float2(v0, v1);
        sA += v0; s2A += v0 * v0;
        sB += v1; s2B += v1 * v1;
    }

    // combine halves (lane l and l+32 hold same features)
    sA  += __shfl_xor(sA, 32, 64);  s2A += __shfl_xor(s2A, 32, 64);
    sB  += __shfl_xor(sB, 32, 64);  s2B += __shfl_xor(s2B, 32, 64);

    __shared__ float smS[4][64];
    __shared__ float smS2[4][64];
    if (half == 0) {
        smS [w][2 * sl]     = sA;  smS [w][2 * sl + 1] = sB;
        smS2[w][2 * sl]     = s2A; smS2[w][2 * sl + 1] = s2B;
    }
    __syncthreads();
    if (tid < 64) {
        float t1 = smS [0][tid] + smS [1][tid] + smS [2][tid] + smS [3][tid];
        float t2 = smS2[0][tid] + smS2[1][tid] + smS2[2][tid] + smS2[3][tid];
        atomicAdd(&stats[tid],      t1);
        atomicAdd(&stats[64 + tid], t2);
    }
}

__global__ void k_bn_final(const float* __restrict__ stats,
                           const float* __restrict__ g,
                           const float* __restrict__ be,
                           float* __restrict__ affine) {
    int c = threadIdx.x;
    if (c < HID) {
        float mu  = stats[c] * (1.0f / N_NODES);
        float var = stats[64 + c] * (1.0f / N_NODES) - mu * mu;
        var = fmaxf(var, 0.f);
        float sc = g[c] * rsqrtf(var + EPS_BN);
        affine[c]       = sc;
        affine[HID + c] = fmaf(-mu, sc, be[c]);
    }
}

// ---------------------------------------------------------------------------
// CSR gather + final fc: out[v] = dot(relu(agg*dinv + b2), fcW) + fcb
// ---------------------------------------------------------------------------
__global__ __launch_bounds__(256) void k_gather_final(const ushort2* __restrict__ ts2,
                                                      const int* __restrict__ rowptr,
                                                      const int* __restrict__ col,
                                                      const float* __restrict__ dinv,
                                                      const float* __restrict__ b2,
                                                      const float* __restrict__ fcW,
                                                      const float* __restrict__ fcb,
                                                      float* __restrict__ out) {
    const int tid  = threadIdx.x;
    const int w    = tid >> 6;
    const int lane = tid & 63;
    const int half = lane >> 5;
    const int sl   = lane & 31;
    const float2 bv = ((const float2*)b2)[sl];
    const float2 fw = ((const float2*)fcW)[sl];
    const float  fb = fcb[0];

    for (int pair = blockIdx.x * 4 + w; pair < N_NODES / 2; pair += gridDim.x * 4) {
        const int node = pair * 2 + half;
        const ushort2 self = ts2[(size_t)node * 32 + sl];
        float acc0 = b2f(self.x), acc1 = b2f(self.y);
        const int e1 = rowptr[node + 1];
        int e = rowptr[node];
        for (; e + 3 < e1; e += 4) {
            const int u0 = col[e], u1 = col[e + 1], u2 = col[e + 2], u3 = col[e + 3];
            const ushort2 a0 = ts2[(size_t)u0 * 32 + sl];
            const ushort2 a1 = ts2[(size_t)u1 * 32 + sl];
            const ushort2 a2 = ts2[(size_t)u2 * 32 + sl];
            const ushort2 a3 = ts2[(size_t)u3 * 32 + sl];
            acc0 += b2f(a0.x) + b2f(a1.x) + b2f(a2.x) + b2f(a3.x);
            acc1 += b2f(a0.y) + b2f(a1.y) + b2f(a2.y) + b2f(a3.y);
        }
        for (; e < e1; ++e) {
            const ushort2 a = ts2[(size_t)col[e] * 32 + sl];
            acc0 += b2f(a.x);
            acc1 += b2f(a.y);
        }
        const float d = dinv[node];
        float v = fmaxf(0.f, fmaf(acc0, d, bv.x)) * fw.x
                + fmaxf(0.f, fmaf(acc1, d, bv.y)) * fw.y;
#pragma unroll
        for (int off = 16; off >= 1; off >>= 1) v += __shfl_xor(v, off, 64);
        if (sl == 0) out[node] = v + fb;
    }
}

// ---------------------------------------------------------------------------
extern "C" void kernel_launch(void* const* d_in, const int* in_sizes, int n_in,
                              void* d_out, int out_size, void* d_ws, size_t ws_size,
                              hipStream_t stream) {
    const float* x    = (const float*)d_in[0];
    const int*   ei   = (const int*)d_in[1];
    const float* W0   = (const float*)d_in[2];
    const float* b0   = (const float*)d_in[3];
    const float* W1   = (const float*)d_in[4];
    const float* b1   = (const float*)d_in[5];
    const float* W2   = (const float*)d_in[6];
    const float* b2   = (const float*)d_in[7];
    const float* g0   = (const float*)d_in[8];
    const float* be0  = (const float*)d_in[9];
    const float* g1   = (const float*)d_in[10];
    const float* be1  = (const float*)d_in[11];
    const float* fcW  = (const float*)d_in[12];
    const float* fcb  = (const float*)d_in[13];
    float* out        = (float*)d_out;

    char* ws = (char*)d_ws;
    size_t off = 0;
    auto alloc = [&](size_t bytes) -> void* {
        size_t o = off;
        off += (bytes + 255) & ~(size_t)255;
        return (void*)(ws + o);
    };
    unsigned short* ts = (unsigned short*)alloc((size_t)N_NODES * HID * 2);  // bf16
    float* bufY    = (float*)alloc((size_t)N_NODES * HID * 4);               // f32
    int*   col     = (int*)  alloc((size_t)N_EDGES * 4);
    float* dinv    = (float*)alloc((size_t)N_NODES * 4);
    int*   counts  = (int*)  alloc((size_t)N_NODES * 4);
    int*   fill    = (int*)  alloc((size_t)N_NODES * 4);
    int*   rowptr  = (int*)  alloc((size_t)(N_NODES + 1) * 4);
    float* stats0  = (float*)alloc(2 * HID * 4);
    float* stats1  = (float*)alloc(2 * HID * 4);
    float* affine0 = (float*)alloc(2 * HID * 4);
    float* affine1 = (float*)alloc(2 * HID * 4);

    const int gN    = (N_NODES + 255) / 256;
    const int gE    = (N_EDGES + 255) / 256;
    const int gGemm = (N_NODES + 63) / 64;
    const int gGath = 2048;

    k_zero<<<gN, 256, 0, stream>>>(counts, fill, stats0, stats1);
    k_count<<<gE, 256, 0, stream>>>(ei, counts);
    k_dinv<<<gN, 256, 0, stream>>>(counts, dinv);
    k_scan<<<1, 1024, 0, stream>>>(counts, rowptr);
    k_scatter<<<gE, 256, 0, stream>>>(ei, rowptr, fill, col);

    // ---- layer 0
    k_gemm<NFEAT, false><<<gGemm, 256, 0, stream>>>(x, W0, dinv, nullptr, ts);
    k_gather_bn<<<gGath, 256, 0, stream>>>((const ushort2*)ts, rowptr, col, dinv, b0, bufY, stats0);
    k_bn_final<<<1, 64, 0, stream>>>(stats0, g0, be0, affine0);

    // ---- layer 1
    k_gemm<HID, true><<<gGemm, 256, 0, stream>>>(bufY, W1, dinv, affine0, ts);
    k_gather_bn<<<gGath, 256, 0, stream>>>((const ushort2*)ts, rowptr, col, dinv, b1, bufY, stats1);
    k_bn_final<<<1, 64, 0, stream>>>(stats1, g1, be1, affine1);

    // ---- layer 2
    k_gemm<HID, true><<<gGemm, 256, 0, stream>>>(bufY, W2, dinv, affine1, ts);
    k_gather_final<<<gGath, 256, 0, stream>>>((const ushort2*)ts, rowptr, col, dinv, b2, fcW, fcb, out);
}

// Round 4
// 343.552 us; speedup vs baseline: 2.3057x; 1.2662x over previous
//
#include <hip/hip_runtime.h>

#define N_NODES 50000
#define N_EDGES 800000
#define NFEAT   128
#define HID     64
#define EPS_BN  1e-5f
#define NBLK_SCAN ((N_NODES + 255) / 256)   // 196

// bf16 <-> f32 helpers (RNE on store)
__device__ __forceinline__ float b2f(unsigned short u) {
    union { unsigned int i; float f; } c;
    c.i = ((unsigned int)u) << 16;
    return c.f;
}
__device__ __forceinline__ unsigned short f2b(float f) {
    union { float f; unsigned int i; } c;
    c.f = f;
    unsigned int i = c.i;
    return (unsigned short)((i + 0x7fffu + ((i >> 16) & 1u)) >> 16);
}

// ---------------------------------------------------------------------------
// CSR build
// ---------------------------------------------------------------------------
__global__ void k_zero(int* __restrict__ counts, int* __restrict__ fill,
                       float* __restrict__ st0, float* __restrict__ st1) {
    int i = blockIdx.x * 256 + threadIdx.x;
    if (i < N_NODES) { counts[i] = 0; fill[i] = 0; }
    if (i < 2 * HID) { st0[i] = 0.f; st1[i] = 0.f; }
}

__global__ void k_count(const int* __restrict__ ei, int* __restrict__ counts) {
    int e = blockIdx.x * 256 + threadIdx.x;
    if (e < N_EDGES) atomicAdd(&counts[ei[N_EDGES + e]], 1);
}

// phase 1: per-block exclusive scan into rowptr, block sums out; fold dinv
__global__ __launch_bounds__(256) void k_scan1(const int* __restrict__ counts,
                                               int* __restrict__ rowptr,
                                               int* __restrict__ bsum,
                                               float* __restrict__ dinv) {
    const int tid = threadIdx.x;
    const int i   = blockIdx.x * 256 + tid;
    int v = (i < N_NODES) ? counts[i] : 0;
    if (i < N_NODES) dinv[i] = rsqrtf((float)(v + 1));   // +1 self loop
    __shared__ int sm[256];
    sm[tid] = v;
    __syncthreads();
    for (int off = 1; off < 256; off <<= 1) {
        int t = (tid >= off) ? sm[tid - off] : 0;
        __syncthreads();
        sm[tid] += t;
        __syncthreads();
    }
    if (i < N_NODES) rowptr[i] = sm[tid] - v;            // local exclusive
    if (tid == 255) bsum[blockIdx.x] = sm[255];
}

// phase 2: exclusive scan of 196 block sums (one block)
__global__ __launch_bounds__(256) void k_scan2(const int* __restrict__ bsum,
                                               int* __restrict__ boff) {
    const int tid = threadIdx.x;
    int v = (tid < NBLK_SCAN) ? bsum[tid] : 0;
    __shared__ int sm[256];
    sm[tid] = v;
    __syncthreads();
    for (int off = 1; off < 256; off <<= 1) {
        int t = (tid >= off) ? sm[tid - off] : 0;
        __syncthreads();
        sm[tid] += t;
        __syncthreads();
    }
    if (tid < NBLK_SCAN) boff[tid] = sm[tid] - v;
}

// phase 3: add block offsets
__global__ __launch_bounds__(256) void k_scan3(int* __restrict__ rowptr,
                                               const int* __restrict__ boff) {
    const int i = blockIdx.x * 256 + threadIdx.x;
    if (i < N_NODES) rowptr[i] += boff[blockIdx.x];
    if (i == 0) rowptr[N_NODES] = N_EDGES;
}

__global__ void k_scatter(const int* __restrict__ ei, const int* __restrict__ rowptr,
                          int* __restrict__ fill, int* __restrict__ col) {
    int e = blockIdx.x * 256 + threadIdx.x;
    if (e >= N_EDGES) return;
    int s = ei[e];
    int t = ei[N_EDGES + e];
    int pos = rowptr[t] + atomicAdd(&fill[t], 1);
    col[pos] = s;
}

// ---------------------------------------------------------------------------
// GEMM: ts[row][col] = bf16( dinv[row] * sum_k Hin[row][k] * W[k][col] )
// ---------------------------------------------------------------------------
template <int K, bool AFFINE>
__global__ __launch_bounds__(256) void k_gemm(const float* __restrict__ H,
                                              const float* __restrict__ W,
                                              const float* __restrict__ dinv,
                                              const float* __restrict__ affine,
                                              unsigned short* __restrict__ ts) {
    __shared__ float Ws[K * HID];
    __shared__ float Hs[64 * K];
    const int tid  = threadIdx.x;
    const int row0 = blockIdx.x * 64;

    for (int i = tid * 4; i < K * HID; i += 256 * 4)
        *(float4*)&Ws[i] = *(const float4*)&W[i];

    for (int i = tid * 4; i < 64 * K; i += 256 * 4) {
        const int r   = i / K;
        const int c   = i % K;
        const int row = row0 + r;
        float4 v = make_float4(0.f, 0.f, 0.f, 0.f);
        if (row < N_NODES) v = *(const float4*)&H[(size_t)row * K + c];
        if (AFFINE) {
            v.x = fmaxf(0.f, fmaf(v.x, affine[c + 0], affine[HID + c + 0]));
            v.y = fmaxf(0.f, fmaf(v.y, affine[c + 1], affine[HID + c + 1]));
            v.z = fmaxf(0.f, fmaf(v.z, affine[c + 2], affine[HID + c + 2]));
            v.w = fmaxf(0.f, fmaf(v.w, affine[c + 3], affine[HID + c + 3]));
        }
        *(float4*)&Hs[i] = v;
    }
    __syncthreads();

    const int col2 = (tid & 31) * 2;
    const int ty   = tid >> 5;            // 0..7
    for (int r = ty; r < 64; r += 8) {
        float a0 = 0.f, a1 = 0.f;
#pragma unroll 8
        for (int k = 0; k < K; ++k) {
            const float h = Hs[r * K + k];
            a0 = fmaf(h, Ws[k * HID + col2],     a0);
            a1 = fmaf(h, Ws[k * HID + col2 + 1], a1);
        }
        const int row = row0 + r;
        if (row < N_NODES) {
            const float d = dinv[row];
            ushort2 o;
            o.x = f2b(a0 * d);
            o.y = f2b(a1 * d);
            *(ushort2*)&ts[(size_t)row * HID + col2] = o;
        }
    }
}

// ---------------------------------------------------------------------------
// CSR gather (bf16 ts) + BN epilogue. 4 nodes per wave: 16-lane group per
// node, lane owns features {4sl..4sl+3} (ushort4). Unroll x4 -> 16
// outstanding row-gathers per wave.
// ---------------------------------------------------------------------------
__global__ __launch_bounds__(256) void k_gather_bn(const ushort4* __restrict__ ts4,
                                                   const int* __restrict__ rowptr,
                                                   const int* __restrict__ col,
                                                   const float* __restrict__ dinv,
                                                   const float* __restrict__ bias,
                                                   float* __restrict__ y,
                                                   float* __restrict__ stats) {
    const int tid  = threadIdx.x;
    const int w    = tid >> 6;
    const int lane = tid & 63;
    const int grp  = lane >> 4;          // 0..3
    const int sl   = lane & 15;          // 0..15
    const float4 bv = ((const float4*)bias)[sl];
    float s0 = 0.f, s1 = 0.f, s2 = 0.f, s3 = 0.f;
    float q0 = 0.f, q1 = 0.f, q2 = 0.f, q3 = 0.f;

    const int nwaves = gridDim.x * 4;
    for (int quad = blockIdx.x * 4 + w; quad < N_NODES / 4; quad += nwaves) {
        const int node = quad * 4 + grp;
        const ushort4 self = ts4[(size_t)node * 16 + sl];
        float a0 = b2f(self.x), a1 = b2f(self.y), a2 = b2f(self.z), a3 = b2f(self.w);
        const int e1 = rowptr[node + 1];
        int e = rowptr[node];
        for (; e + 3 < e1; e += 4) {
            const int u0 = col[e], u1 = col[e + 1], u2 = col[e + 2], u3 = col[e + 3];
            const ushort4 t0 = ts4[(size_t)u0 * 16 + sl];
            const ushort4 t1 = ts4[(size_t)u1 * 16 + sl];
            const ushort4 t2 = ts4[(size_t)u2 * 16 + sl];
            const ushort4 t3 = ts4[(size_t)u3 * 16 + sl];
            a0 += b2f(t0.x) + b2f(t1.x) + b2f(t2.x) + b2f(t3.x);
            a1 += b2f(t0.y) + b2f(t1.y) + b2f(t2.y) + b2f(t3.y);
            a2 += b2f(t0.z) + b2f(t1.z) + b2f(t2.z) + b2f(t3.z);
            a3 += b2f(t0.w) + b2f(t1.w) + b2f(t2.w) + b2f(t3.w);
        }
        for (; e < e1; ++e) {
            const ushort4 t = ts4[(size_t)col[e] * 16 + sl];
            a0 += b2f(t.x); a1 += b2f(t.y); a2 += b2f(t.z); a3 += b2f(t.w);
        }
        const float d  = dinv[node];
        const float v0 = fmaf(a0, d, bv.x);
        const float v1 = fmaf(a1, d, bv.y);
        const float v2 = fmaf(a2, d, bv.z);
        const float v3 = fmaf(a3, d, bv.w);
        ((float4*)y)[(size_t)node * 16 + sl] = make_float4(v0, v1, v2, v3);
        s0 += v0; q0 += v0 * v0;
        s1 += v1; q1 += v1 * v1;
        s2 += v2; q2 += v2 * v2;
        s3 += v3; q3 += v3 * v3;
    }

    // combine the 4 groups (same feature slot sl)
#pragma unroll
    for (int off = 16; off <= 32; off <<= 1) {
        s0 += __shfl_xor(s0, off, 64); q0 += __shfl_xor(q0, off, 64);
        s1 += __shfl_xor(s1, off, 64); q1 += __shfl_xor(q1, off, 64);
        s2 += __shfl_xor(s2, off, 64); q2 += __shfl_xor(q2, off, 64);
        s3 += __shfl_xor(s3, off, 64); q3 += __shfl_xor(q3, off, 64);
    }
    __shared__ float smS[4][64];
    __shared__ float smQ[4][64];
    if (grp == 0) {
        *(float4*)&smS[w][4 * sl] = make_float4(s0, s1, s2, s3);
        *(float4*)&smQ[w][4 * sl] = make_float4(q0, q1, q2, q3);
    }
    __syncthreads();
    if (tid < 64) {
        float t1 = smS[0][tid] + smS[1][tid] + smS[2][tid] + smS[3][tid];
        float t2 = smQ[0][tid] + smQ[1][tid] + smQ[2][tid] + smQ[3][tid];
        atomicAdd(&stats[tid],      t1);
        atomicAdd(&stats[64 + tid], t2);
    }
}

__global__ void k_bn_final(const float* __restrict__ stats,
                           const float* __restrict__ g,
                           const float* __restrict__ be,
                           float* __restrict__ affine) {
    int c = threadIdx.x;
    if (c < HID) {
        float mu  = stats[c] * (1.0f / N_NODES);
        float var = stats[64 + c] * (1.0f / N_NODES) - mu * mu;
        var = fmaxf(var, 0.f);
        float sc = g[c] * rsqrtf(var + EPS_BN);
        affine[c]       = sc;
        affine[HID + c] = fmaf(-mu, sc, be[c]);
    }
}

// ---------------------------------------------------------------------------
// CSR gather + final fc: out[v] = dot(relu(agg*dinv + b2), fcW) + fcb
// ---------------------------------------------------------------------------
__global__ __launch_bounds__(256) void k_gather_final(const ushort4* __restrict__ ts4,
                                                      const int* __restrict__ rowptr,
                                                      const int* __restrict__ col,
                                                      const float* __restrict__ dinv,
                                                      const float* __restrict__ b2,
                                                      const float* __restrict__ fcW,
                                                      const float* __restrict__ fcb,
                                                      float* __restrict__ out) {
    const int tid  = threadIdx.x;
    const int w    = tid >> 6;
    const int lane = tid & 63;
    const int grp  = lane >> 4;
    const int sl   = lane & 15;
    const float4 bv = ((const float4*)b2)[sl];
    const float4 fw = ((const float4*)fcW)[sl];
    const float  fb = fcb[0];

    const int nwaves = gridDim.x * 4;
    for (int quad = blockIdx.x * 4 + w; quad < N_NODES / 4; quad += nwaves) {
        const int node = quad * 4 + grp;
        const ushort4 self = ts4[(size_t)node * 16 + sl];
        float a0 = b2f(self.x), a1 = b2f(self.y), a2 = b2f(self.z), a3 = b2f(self.w);
        const int e1 = rowptr[node + 1];
        int e = rowptr[node];
        for (; e + 3 < e1; e += 4) {
            const int u0 = col[e], u1 = col[e + 1], u2 = col[e + 2], u3 = col[e + 3];
            const ushort4 t0 = ts4[(size_t)u0 * 16 + sl];
            const ushort4 t1 = ts4[(size_t)u1 * 16 + sl];
            const ushort4 t2 = ts4[(size_t)u2 * 16 + sl];
            const ushort4 t3 = ts4[(size_t)u3 * 16 + sl];
            a0 += b2f(t0.x) + b2f(t1.x) + b2f(t2.x) + b2f(t3.x);
            a1 += b2f(t0.y) + b2f(t1.y) + b2f(t2.y) + b2f(t3.y);
            a2 += b2f(t0.z) + b2f(t1.z) + b2f(t2.z) + b2f(t3.z);
            a3 += b2f(t0.w) + b2f(t1.w) + b2f(t2.w) + b2f(t3.w);
        }
        for (; e < e1; ++e) {
            const ushort4 t = ts4[(size_t)col[e] * 16 + sl];
            a0 += b2f(t.x); a1 += b2f(t.y); a2 += b2f(t.z); a3 += b2f(t.w);
        }
        const float d = dinv[node];
        float v = fmaxf(0.f, fmaf(a0, d, bv.x)) * fw.x
                + fmaxf(0.f, fmaf(a1, d, bv.y)) * fw.y
                + fmaxf(0.f, fmaf(a2, d, bv.z)) * fw.z
                + fmaxf(0.f, fmaf(a3, d, bv.w)) * fw.w;
#pragma unroll
        for (int off = 8; off >= 1; off >>= 1) v += __shfl_xor(v, off, 64);
        if (sl == 0) out[node] = v + fb;
    }
}

// ---------------------------------------------------------------------------
extern "C" void kernel_launch(void* const* d_in, const int* in_sizes, int n_in,
                              void* d_out, int out_size, void* d_ws, size_t ws_size,
                              hipStream_t stream) {
    const float* x    = (const float*)d_in[0];
    const int*   ei   = (const int*)d_in[1];
    const float* W0   = (const float*)d_in[2];
    const float* b0   = (const float*)d_in[3];
    const float* W1   = (const float*)d_in[4];
    const float* b1   = (const float*)d_in[5];
    const float* W2   = (const float*)d_in[6];
    const float* b2   = (const float*)d_in[7];
    const float* g0   = (const float*)d_in[8];
    const float* be0  = (const float*)d_in[9];
    const float* g1   = (const float*)d_in[10];
    const float* be1  = (const float*)d_in[11];
    const float* fcW  = (const float*)d_in[12];
    const float* fcb  = (const float*)d_in[13];
    float* out        = (float*)d_out;

    char* ws = (char*)d_ws;
    size_t off = 0;
    auto alloc = [&](size_t bytes) -> void* {
        size_t o = off;
        off += (bytes + 255) & ~(size_t)255;
        return (void*)(ws + o);
    };
    unsigned short* ts = (unsigned short*)alloc((size_t)N_NODES * HID * 2);
    float* bufY    = (float*)alloc((size_t)N_NODES * HID * 4);
    int*   col     = (int*)  alloc((size_t)N_EDGES * 4);
    float* dinv    = (float*)alloc((size_t)N_NODES * 4);
    int*   counts  = (int*)  alloc((size_t)N_NODES * 4);
    int*   fill    = (int*)  alloc((size_t)N_NODES * 4);
    int*   rowptr  = (int*)  alloc((size_t)(N_NODES + 1) * 4);
    int*   bsum    = (int*)  alloc((size_t)NBLK_SCAN * 4);
    int*   boff    = (int*)  alloc((size_t)NBLK_SCAN * 4);
    float* stats0  = (float*)alloc(2 * HID * 4);
    float* stats1  = (float*)alloc(2 * HID * 4);
    float* affine0 = (float*)alloc(2 * HID * 4);
    float* affine1 = (float*)alloc(2 * HID * 4);

    const int gN    = (N_NODES + 255) / 256;
    const int gE    = (N_EDGES + 255) / 256;
    const int gGemm = (N_NODES + 63) / 64;
    const int gGath = 2048;

    k_zero<<<gN, 256, 0, stream>>>(counts, fill, stats0, stats1);
    k_count<<<gE, 256, 0, stream>>>(ei, counts);
    k_scan1<<<NBLK_SCAN, 256, 0, stream>>>(counts, rowptr, bsum, dinv);
    k_scan2<<<1, 256, 0, stream>>>(bsum, boff);
    k_scan3<<<NBLK_SCAN, 256, 0, stream>>>(rowptr, boff);
    k_scatter<<<gE, 256, 0, stream>>>(ei, rowptr, fill, col);

    // ---- layer 0
    k_gemm<NFEAT, false><<<gGemm, 256, 0, stream>>>(x, W0, dinv, nullptr, ts);
    k_gather_bn<<<gGath, 256, 0, stream>>>((const ushort4*)ts, rowptr, col, dinv, b0, bufY, stats0);
    k_bn_final<<<1, 64, 0, stream>>>(stats0, g0, be0, affine0);

    // ---- layer 1
    k_gemm<HID, true><<<gGemm, 256, 0, stream>>>(bufY, W1, dinv, affine0, ts);
    k_gather_bn<<<gGath, 256, 0, stream>>>((const ushort4*)ts, rowptr, col, dinv, b1, bufY, stats1);
    k_bn_final<<<1, 64, 0, stream>>>(stats1, g1, be1, affine1);

    // ---- layer 2
    k_gemm<HID, true><<<gGemm, 256, 0, stream>>>(bufY, W2, dinv, affine1, ts);
    k_gather_final<<<gGath, 256, 0, stream>>>((const ushort4*)ts, rowptr, col, dinv, b2, fcW, fcb, out);
}

// Round 5
// 331.799 us; speedup vs baseline: 2.3874x; 1.0354x over previous
//
#include <hip/hip_runtime.h>

#define N_NODES 50000
#define N_EDGES 800000
#define NFEAT   128
#define HID     64
#define EPS_BN  1e-5f
#define NBLK_SCAN ((N_NODES + 255) / 256)   // 196

// bf16 helpers
__device__ __forceinline__ float u2f_lo(unsigned int u) {
    union { unsigned int i; float f; } c; c.i = u << 16; return c.f;
}
__device__ __forceinline__ float u2f_hi(unsigned int u) {
    union { unsigned int i; float f; } c; c.i = u & 0xffff0000u; return c.f;
}
__device__ __forceinline__ unsigned short f2b(float f) {
    union { float f; unsigned int i; } c;
    c.f = f;
    unsigned int i = c.i;
    return (unsigned short)((i + 0x7fffu + ((i >> 16) & 1u)) >> 16);
}

// ---------------------------------------------------------------------------
// CSR build
// ---------------------------------------------------------------------------
__global__ void k_zero(int* __restrict__ counts, int* __restrict__ fill,
                       float* __restrict__ st0, float* __restrict__ st1) {
    int i = blockIdx.x * 256 + threadIdx.x;
    if (i < N_NODES) { counts[i] = 0; fill[i] = 0; }
    if (i < 2 * HID) { st0[i] = 0.f; st1[i] = 0.f; }
}

__global__ void k_count(const int* __restrict__ ei, int* __restrict__ counts) {
    int e = blockIdx.x * 256 + threadIdx.x;
    if (e < N_EDGES) atomicAdd(&counts[ei[N_EDGES + e]], 1);
}

__global__ __launch_bounds__(256) void k_scan1(const int* __restrict__ counts,
                                               int* __restrict__ rowptr,
                                               int* __restrict__ bsum,
                                               float* __restrict__ dinv) {
    const int tid = threadIdx.x;
    const int i   = blockIdx.x * 256 + tid;
    int v = (i < N_NODES) ? counts[i] : 0;
    if (i < N_NODES) dinv[i] = rsqrtf((float)(v + 1));   // +1 self loop
    __shared__ int sm[256];
    sm[tid] = v;
    __syncthreads();
    for (int off = 1; off < 256; off <<= 1) {
        int t = (tid >= off) ? sm[tid - off] : 0;
        __syncthreads();
        sm[tid] += t;
        __syncthreads();
    }
    if (i < N_NODES) rowptr[i] = sm[tid] - v;
    if (tid == 255) bsum[blockIdx.x] = sm[255];
}

__global__ __launch_bounds__(256) void k_scan2(const int* __restrict__ bsum,
                                               int* __restrict__ boff) {
    const int tid = threadIdx.x;
    int v = (tid < NBLK_SCAN) ? bsum[tid] : 0;
    __shared__ int sm[256];
    sm[tid] = v;
    __syncthreads();
    for (int off = 1; off < 256; off <<= 1) {
        int t = (tid >= off) ? sm[tid - off] : 0;
        __syncthreads();
        sm[tid] += t;
        __syncthreads();
    }
    if (tid < NBLK_SCAN) boff[tid] = sm[tid] - v;
}

__global__ __launch_bounds__(256) void k_scan3(int* __restrict__ rowptr,
                                               const int* __restrict__ boff) {
    const int i = blockIdx.x * 256 + threadIdx.x;
    if (i < N_NODES) rowptr[i] += boff[blockIdx.x];
    if (i == 0) rowptr[N_NODES] = N_EDGES;
}

__global__ void k_scatter(const int* __restrict__ ei, const int* __restrict__ rowptr,
                          int* __restrict__ fill, int* __restrict__ col) {
    int e = blockIdx.x * 256 + threadIdx.x;
    if (e >= N_EDGES) return;
    int s = ei[e];
    int t = ei[N_EDGES + e];
    int pos = rowptr[t] + atomicAdd(&fill[t], 1);
    col[pos] = s;
}

// ---------------------------------------------------------------------------
// GEMM: ts[row][col] = bf16( dinv[row] * sum_k Hin[row][k] * W[k][col] )
// ---------------------------------------------------------------------------
template <int K, bool AFFINE>
__global__ __launch_bounds__(256) void k_gemm(const float* __restrict__ H,
                                              const float* __restrict__ W,
                                              const float* __restrict__ dinv,
                                              const float* __restrict__ affine,
                                              unsigned short* __restrict__ ts) {
    __shared__ float Ws[K * HID];
    __shared__ float Hs[64 * K];
    const int tid  = threadIdx.x;
    const int row0 = blockIdx.x * 64;

    for (int i = tid * 4; i < K * HID; i += 256 * 4)
        *(float4*)&Ws[i] = *(const float4*)&W[i];

    for (int i = tid * 4; i < 64 * K; i += 256 * 4) {
        const int r   = i / K;
        const int c   = i % K;
        const int row = row0 + r;
        float4 v = make_float4(0.f, 0.f, 0.f, 0.f);
        if (row < N_NODES) v = *(const float4*)&H[(size_t)row * K + c];
        if (AFFINE) {
            v.x = fmaxf(0.f, fmaf(v.x, affine[c + 0], affine[HID + c + 0]));
            v.y = fmaxf(0.f, fmaf(v.y, affine[c + 1], affine[HID + c + 1]));
            v.z = fmaxf(0.f, fmaf(v.z, affine[c + 2], affine[HID + c + 2]));
            v.w = fmaxf(0.f, fmaf(v.w, affine[c + 3], affine[HID + c + 3]));
        }
        *(float4*)&Hs[i] = v;
    }
    __syncthreads();

    const int col2 = (tid & 31) * 2;
    const int ty   = tid >> 5;
    for (int r = ty; r < 64; r += 8) {
        float a0 = 0.f, a1 = 0.f;
#pragma unroll 8
        for (int k = 0; k < K; ++k) {
            const float h = Hs[r * K + k];
            a0 = fmaf(h, Ws[k * HID + col2],     a0);
            a1 = fmaf(h, Ws[k * HID + col2 + 1], a1);
        }
        const int row = row0 + r;
        if (row < N_NODES) {
            const float d = dinv[row];
            ushort2 o;
            o.x = f2b(a0 * d);
            o.y = f2b(a1 * d);
            *(ushort2*)&ts[(size_t)row * HID + col2] = o;
        }
    }
}

#define ACC8(r)                                             \
    a0 += u2f_lo(r.x); a1 += u2f_hi(r.x);                   \
    a2 += u2f_lo(r.y); a3 += u2f_hi(r.y);                   \
    a4 += u2f_lo(r.z); a5 += u2f_hi(r.z);                   \
    a6 += u2f_lo(r.w); a7 += u2f_hi(r.w);

// ---------------------------------------------------------------------------
// CSR gather (bf16 ts) + BN epilogue. 8 nodes per wave: 8-lane group per
// node, lane owns 8 features via one uint4 (16B) -> dense 128B row per group.
// Unroll x4 => 4KB outstanding per wave.
// ---------------------------------------------------------------------------
__global__ __launch_bounds__(256) void k_gather_bn(const uint4* __restrict__ ts8,
                                                   const int* __restrict__ rowptr,
                                                   const int* __restrict__ col,
                                                   const float* __restrict__ dinv,
                                                   const float* __restrict__ bias,
                                                   float* __restrict__ y,
                                                   float* __restrict__ stats) {
    const int tid  = threadIdx.x;
    const int w    = tid >> 6;
    const int lane = tid & 63;
    const int grp  = lane >> 3;          // 0..7
    const int sl   = lane & 7;           // 0..7, owns features 8sl..8sl+7
    const float4 bv0 = ((const float4*)bias)[2 * sl];
    const float4 bv1 = ((const float4*)bias)[2 * sl + 1];
    float s0=0.f,s1=0.f,s2=0.f,s3=0.f,s4=0.f,s5=0.f,s6=0.f,s7=0.f;
    float q0=0.f,q1=0.f,q2=0.f,q3=0.f,q4=0.f,q5=0.f,q6=0.f,q7=0.f;

    for (int oct = blockIdx.x * 4 + w; oct < N_NODES / 8; oct += gridDim.x * 4) {
        const int node = oct * 8 + grp;
        const uint4 self = ts8[(size_t)node * 8 + sl];
        float a0 = u2f_lo(self.x), a1 = u2f_hi(self.x);
        float a2 = u2f_lo(self.y), a3 = u2f_hi(self.y);
        float a4 = u2f_lo(self.z), a5 = u2f_hi(self.z);
        float a6 = u2f_lo(self.w), a7 = u2f_hi(self.w);
        const int e1 = rowptr[node + 1];
        int e = rowptr[node];
        for (; e + 3 < e1; e += 4) {
            const int u0 = col[e], u1 = col[e + 1], u2 = col[e + 2], u3 = col[e + 3];
            const uint4 r0 = ts8[(size_t)u0 * 8 + sl];
            const uint4 r1 = ts8[(size_t)u1 * 8 + sl];
            const uint4 r2 = ts8[(size_t)u2 * 8 + sl];
            const uint4 r3 = ts8[(size_t)u3 * 8 + sl];
            ACC8(r0) ACC8(r1) ACC8(r2) ACC8(r3)
        }
        for (; e < e1; ++e) {
            const uint4 r = ts8[(size_t)col[e] * 8 + sl];
            ACC8(r)
        }
        const float d = dinv[node];
        const float v0 = fmaf(a0, d, bv0.x), v1 = fmaf(a1, d, bv0.y);
        const float v2 = fmaf(a2, d, bv0.z), v3 = fmaf(a3, d, bv0.w);
        const float v4 = fmaf(a4, d, bv1.x), v5 = fmaf(a5, d, bv1.y);
        const float v6 = fmaf(a6, d, bv1.z), v7 = fmaf(a7, d, bv1.w);
        float4* yr = (float4*)y + (size_t)node * 16 + 2 * sl;
        yr[0] = make_float4(v0, v1, v2, v3);
        yr[1] = make_float4(v4, v5, v6, v7);
        s0 += v0; q0 += v0 * v0;  s1 += v1; q1 += v1 * v1;
        s2 += v2; q2 += v2 * v2;  s3 += v3; q3 += v3 * v3;
        s4 += v4; q4 += v4 * v4;  s5 += v5; q5 += v5 * v5;
        s6 += v6; q6 += v6 * v6;  s7 += v7; q7 += v7 * v7;
    }

    // combine the 8 groups (same feature slot sl)
#pragma unroll
    for (int off = 8; off <= 32; off <<= 1) {
        s0 += __shfl_xor(s0, off, 64); q0 += __shfl_xor(q0, off, 64);
        s1 += __shfl_xor(s1, off, 64); q1 += __shfl_xor(q1, off, 64);
        s2 += __shfl_xor(s2, off, 64); q2 += __shfl_xor(q2, off, 64);
        s3 += __shfl_xor(s3, off, 64); q3 += __shfl_xor(q3, off, 64);
        s4 += __shfl_xor(s4, off, 64); q4 += __shfl_xor(q4, off, 64);
        s5 += __shfl_xor(s5, off, 64); q5 += __shfl_xor(q5, off, 64);
        s6 += __shfl_xor(s6, off, 64); q6 += __shfl_xor(q6, off, 64);
        s7 += __shfl_xor(s7, off, 64); q7 += __shfl_xor(q7, off, 64);
    }
    __shared__ float smS[4][64];
    __shared__ float smQ[4][64];
    if (grp == 0) {
        *(float4*)&smS[w][8 * sl]     = make_float4(s0, s1, s2, s3);
        *(float4*)&smS[w][8 * sl + 4] = make_float4(s4, s5, s6, s7);
        *(float4*)&smQ[w][8 * sl]     = make_float4(q0, q1, q2, q3);
        *(float4*)&smQ[w][8 * sl + 4] = make_float4(q4, q5, q6, q7);
    }
    __syncthreads();
    if (tid < 64) {
        float t1 = smS[0][tid] + smS[1][tid] + smS[2][tid] + smS[3][tid];
        float t2 = smQ[0][tid] + smQ[1][tid] + smQ[2][tid] + smQ[3][tid];
        atomicAdd(&stats[tid],      t1);
        atomicAdd(&stats[64 + tid], t2);
    }
}

__global__ void k_bn_final(const float* __restrict__ stats,
                           const float* __restrict__ g,
                           const float* __restrict__ be,
                           float* __restrict__ affine) {
    int c = threadIdx.x;
    if (c < HID) {
        float mu  = stats[c] * (1.0f / N_NODES);
        float var = stats[64 + c] * (1.0f / N_NODES) - mu * mu;
        var = fmaxf(var, 0.f);
        float sc = g[c] * rsqrtf(var + EPS_BN);
        affine[c]       = sc;
        affine[HID + c] = fmaf(-mu, sc, be[c]);
    }
}

// ---------------------------------------------------------------------------
// CSR gather + final fc: out[v] = dot(relu(agg*dinv + b2), fcW) + fcb
// ---------------------------------------------------------------------------
__global__ __launch_bounds__(256) void k_gather_final(const uint4* __restrict__ ts8,
                                                      const int* __restrict__ rowptr,
                                                      const int* __restrict__ col,
                                                      const float* __restrict__ dinv,
                                                      const float* __restrict__ b2,
                                                      const float* __restrict__ fcW,
                                                      const float* __restrict__ fcb,
                                                      float* __restrict__ out) {
    const int tid  = threadIdx.x;
    const int w    = tid >> 6;
    const int lane = tid & 63;
    const int grp  = lane >> 3;
    const int sl   = lane & 7;
    const float4 bv0 = ((const float4*)b2)[2 * sl];
    const float4 bv1 = ((const float4*)b2)[2 * sl + 1];
    const float4 fw0 = ((const float4*)fcW)[2 * sl];
    const float4 fw1 = ((const float4*)fcW)[2 * sl + 1];
    const float  fb  = fcb[0];

    for (int oct = blockIdx.x * 4 + w; oct < N_NODES / 8; oct += gridDim.x * 4) {
        const int node = oct * 8 + grp;
        const uint4 self = ts8[(size_t)node * 8 + sl];
        float a0 = u2f_lo(self.x), a1 = u2f_hi(self.x);
        float a2 = u2f_lo(self.y), a3 = u2f_hi(self.y);
        float a4 = u2f_lo(self.z), a5 = u2f_hi(self.z);
        float a6 = u2f_lo(self.w), a7 = u2f_hi(self.w);
        const int e1 = rowptr[node + 1];
        int e = rowptr[node];
        for (; e + 3 < e1; e += 4) {
            const int u0 = col[e], u1 = col[e + 1], u2 = col[e + 2], u3 = col[e + 3];
            const uint4 r0 = ts8[(size_t)u0 * 8 + sl];
            const uint4 r1 = ts8[(size_t)u1 * 8 + sl];
            const uint4 r2 = ts8[(size_t)u2 * 8 + sl];
            const uint4 r3 = ts8[(size_t)u3 * 8 + sl];
            ACC8(r0) ACC8(r1) ACC8(r2) ACC8(r3)
        }
        for (; e < e1; ++e) {
            const uint4 r = ts8[(size_t)col[e] * 8 + sl];
            ACC8(r)
        }
        const float d = dinv[node];
        float v = fmaxf(0.f, fmaf(a0, d, bv0.x)) * fw0.x
                + fmaxf(0.f, fmaf(a1, d, bv0.y)) * fw0.y
                + fmaxf(0.f, fmaf(a2, d, bv0.z)) * fw0.z
                + fmaxf(0.f, fmaf(a3, d, bv0.w)) * fw0.w
                + fmaxf(0.f, fmaf(a4, d, bv1.x)) * fw1.x
                + fmaxf(0.f, fmaf(a5, d, bv1.y)) * fw1.y
                + fmaxf(0.f, fmaf(a6, d, bv1.z)) * fw1.z
                + fmaxf(0.f, fmaf(a7, d, bv1.w)) * fw1.w;
#pragma unroll
        for (int off = 4; off >= 1; off >>= 1) v += __shfl_xor(v, off, 64);
        if (sl == 0) out[node] = v + fb;
    }
}

// ---------------------------------------------------------------------------
extern "C" void kernel_launch(void* const* d_in, const int* in_sizes, int n_in,
                              void* d_out, int out_size, void* d_ws, size_t ws_size,
                              hipStream_t stream) {
    const float* x    = (const float*)d_in[0];
    const int*   ei   = (const int*)d_in[1];
    const float* W0   = (const float*)d_in[2];
    const float* b0   = (const float*)d_in[3];
    const float* W1   = (const float*)d_in[4];
    const float* b1   = (const float*)d_in[5];
    const float* W2   = (const float*)d_in[6];
    const float* b2   = (const float*)d_in[7];
    const float* g0   = (const float*)d_in[8];
    const float* be0  = (const float*)d_in[9];
    const float* g1   = (const float*)d_in[10];
    const float* be1  = (const float*)d_in[11];
    const float* fcW  = (const float*)d_in[12];
    const float* fcb  = (const float*)d_in[13];
    float* out        = (float*)d_out;

    char* ws = (char*)d_ws;
    size_t off = 0;
    auto alloc = [&](size_t bytes) -> void* {
        size_t o = off;
        off += (bytes + 255) & ~(size_t)255;
        return (void*)(ws + o);
    };
    unsigned short* ts = (unsigned short*)alloc((size_t)N_NODES * HID * 2);
    float* bufY    = (float*)alloc((size_t)N_NODES * HID * 4);
    int*   col     = (int*)  alloc((size_t)N_EDGES * 4);
    float* dinv    = (float*)alloc((size_t)N_NODES * 4);
    int*   counts  = (int*)  alloc((size_t)N_NODES * 4);
    int*   fill    = (int*)  alloc((size_t)N_NODES * 4);
    int*   rowptr  = (int*)  alloc((size_t)(N_NODES + 1) * 4);
    int*   bsum    = (int*)  alloc((size_t)NBLK_SCAN * 4);
    int*   boff    = (int*)  alloc((size_t)NBLK_SCAN * 4);
    float* stats0  = (float*)alloc(2 * HID * 4);
    float* stats1  = (float*)alloc(2 * HID * 4);
    float* affine0 = (float*)alloc(2 * HID * 4);
    float* affine1 = (float*)alloc(2 * HID * 4);

    const int gN    = (N_NODES + 255) / 256;
    const int gE    = (N_EDGES + 255) / 256;
    const int gGemm = (N_NODES + 63) / 64;
    const int gGath = (N_NODES / 8 + 3) / 4;   // one octet per wave

    k_zero<<<gN, 256, 0, stream>>>(counts, fill, stats0, stats1);
    k_count<<<gE, 256, 0, stream>>>(ei, counts);
    k_scan1<<<NBLK_SCAN, 256, 0, stream>>>(counts, rowptr, bsum, dinv);
    k_scan2<<<1, 256, 0, stream>>>(bsum, boff);
    k_scan3<<<NBLK_SCAN, 256, 0, stream>>>(rowptr, boff);
    k_scatter<<<gE, 256, 0, stream>>>(ei, rowptr, fill, col);

    // ---- layer 0
    k_gemm<NFEAT, false><<<gGemm, 256, 0, stream>>>(x, W0, dinv, nullptr, ts);
    k_gather_bn<<<gGath, 256, 0, stream>>>((const uint4*)ts, rowptr, col, dinv, b0, bufY, stats0);
    k_bn_final<<<1, 64, 0, stream>>>(stats0, g0, be0, affine0);

    // ---- layer 1
    k_gemm<HID, true><<<gGemm, 256, 0, stream>>>(bufY, W1, dinv, affine0, ts);
    k_gather_bn<<<gGath, 256, 0, stream>>>((const uint4*)ts, rowptr, col, dinv, b1, bufY, stats1);
    k_bn_final<<<1, 64, 0, stream>>>(stats1, g1, be1, affine1);

    // ---- layer 2
    k_gemm<HID, true><<<gGemm, 256, 0, stream>>>(bufY, W2, dinv, affine1, ts);
    k_gather_final<<<gGath, 256, 0, stream>>>((const uint4*)ts, rowptr, col, dinv, b2, fcW, fcb, out);
}

// Round 6
// 321.354 us; speedup vs baseline: 2.4650x; 1.0325x over previous
//
#include <hip/hip_runtime.h>

#define N_NODES 50000
#define N_EDGES 800000
#define NFEAT   128
#define HID     64
#define EPS_BN  1e-5f
#define NCHUNK  4
#define CHN     (N_NODES / NCHUNK)          // 12500 src nodes per chunk (~1.6 MB of ts)
#define NCNT    (N_NODES * NCHUNK)          // 200000 (row,chunk) buckets
#define NBLK1   ((NCNT + 255) / 256)        // 782

// bf16 helpers
__device__ __forceinline__ float u2f_lo(unsigned int u) {
    union { unsigned int i; float f; } c; c.i = u << 16; return c.f;
}
__device__ __forceinline__ float u2f_hi(unsigned int u) {
    union { unsigned int i; float f; } c; c.i = u & 0xffff0000u; return c.f;
}
__device__ __forceinline__ unsigned int f2b2(float lo, float hi) {
    union { float f; unsigned int i; } a, b;
    a.f = lo; b.f = hi;
    unsigned int x = (a.i + 0x7fffu + ((a.i >> 16) & 1u)) >> 16;
    unsigned int y = (b.i + 0x7fffu + ((b.i >> 16) & 1u)) & 0xffff0000u;
    return x | y;
}

// ---------------------------------------------------------------------------
// CSR build with (row, src-chunk) buckets
// ---------------------------------------------------------------------------
__global__ void k_zero(int* __restrict__ counts, int* __restrict__ fill,
                       float* __restrict__ st0, float* __restrict__ st1) {
    int i = blockIdx.x * 256 + threadIdx.x;
    if (i < NCNT) { counts[i] = 0; fill[i] = 0; }
    if (i < 2 * HID) { st0[i] = 0.f; st1[i] = 0.f; }
}

__global__ void k_count(const int* __restrict__ ei, int* __restrict__ counts) {
    int e = blockIdx.x * 256 + threadIdx.x;
    if (e >= N_EDGES) return;
    int s = ei[e];
    int t = ei[N_EDGES + e];
    atomicAdd(&counts[t * NCHUNK + s / CHN], 1);
}

__global__ __launch_bounds__(256) void k_scan1(const int* __restrict__ counts,
                                               int* __restrict__ rowptr,
                                               int* __restrict__ bsum) {
    const int tid = threadIdx.x;
    const int i   = blockIdx.x * 256 + tid;
    int v = (i < NCNT) ? counts[i] : 0;
    __shared__ int sm[256];
    sm[tid] = v;
    __syncthreads();
    for (int off = 1; off < 256; off <<= 1) {
        int t = (tid >= off) ? sm[tid - off] : 0;
        __syncthreads();
        sm[tid] += t;
        __syncthreads();
    }
    if (i < NCNT) rowptr[i] = sm[tid] - v;
    if (tid == 255) bsum[blockIdx.x] = sm[255];
}

__global__ __launch_bounds__(1024) void k_scan2(const int* __restrict__ bsum,
                                                int* __restrict__ boff) {
    const int tid = threadIdx.x;
    int v = (tid < NBLK1) ? bsum[tid] : 0;
    __shared__ int sm[1024];
    sm[tid] = v;
    __syncthreads();
    for (int off = 1; off < 1024; off <<= 1) {
        int t = (tid >= off) ? sm[tid - off] : 0;
        __syncthreads();
        sm[tid] += t;
        __syncthreads();
    }
    if (tid < NBLK1) boff[tid] = sm[tid] - v;
}

__global__ __launch_bounds__(256) void k_scan3(int* __restrict__ rowptr,
                                               const int* __restrict__ boff) {
    const int i = blockIdx.x * 256 + threadIdx.x;
    if (i < NCNT) rowptr[i] += boff[blockIdx.x];
    if (i == 0) rowptr[NCNT] = N_EDGES;
}

__global__ void k_dinv(const int* __restrict__ rowptr, float* __restrict__ dinv) {
    int i = blockIdx.x * 256 + threadIdx.x;
    if (i < N_NODES)
        dinv[i] = rsqrtf((float)(rowptr[i * NCHUNK + NCHUNK] - rowptr[i * NCHUNK] + 1));
}

__global__ void k_scatter(const int* __restrict__ ei, const int* __restrict__ rowptr,
                          int* __restrict__ fill, int* __restrict__ col) {
    int e = blockIdx.x * 256 + threadIdx.x;
    if (e >= N_EDGES) return;
    int s = ei[e];
    int t = ei[N_EDGES + e];
    int b = t * NCHUNK + s / CHN;
    int pos = rowptr[b] + atomicAdd(&fill[b], 1);
    col[pos] = s;
}

// ---------------------------------------------------------------------------
// GEMM: ts[row][col] = bf16( dinv[row] * sum_k Hin[row][k] * W[k][col] )
// W-only LDS staging; thread = 2 rows x 16 cols register tile; H streamed
// from global (quad-broadcast float4); vectorized ds_read_b128 on W.
// Block covers 128 rows.
// ---------------------------------------------------------------------------
template <int K, bool AFFINE>
__global__ __launch_bounds__(256) void k_gemm(const float* __restrict__ H,
                                              const float* __restrict__ W,
                                              const float* __restrict__ dinv,
                                              const float* __restrict__ affine,
                                              unsigned short* __restrict__ ts) {
    __shared__ float Ws[K * HID];
    __shared__ float As[2 * K];
    const int tid = threadIdx.x;
    for (int i = tid * 4; i < K * HID; i += 256 * 4)
        *(float4*)&Ws[i] = *(const float4*)&W[i];
    if (AFFINE) {
        if (tid < (2 * K) / 4)
            *(float4*)&As[tid * 4] = *(const float4*)&affine[tid * 4];
    }
    __syncthreads();

    const int quad = tid & 3;            // col group: cols quad*16..+15
    const int rp_  = tid >> 2;           // 0..63
    const int row  = blockIdx.x * 128 + rp_ * 2;
    const int c0   = quad * 16;
    const bool v0  = row < N_NODES;
    const bool v1  = row + 1 < N_NODES;

    float acc0[16], acc1[16];
#pragma unroll
    for (int i = 0; i < 16; ++i) { acc0[i] = 0.f; acc1[i] = 0.f; }

    const float* h0p = H + (size_t)row * K;
    const float4 z4 = make_float4(0.f, 0.f, 0.f, 0.f);

#pragma unroll 2
    for (int k = 0; k < K; k += 4) {
        float4 ha = v0 ? *(const float4*)(h0p + k) : z4;
        float4 hb = v1 ? *(const float4*)(h0p + K + k) : z4;
        if (AFFINE) {
            const float4 sc = *(const float4*)&As[k];
            const float4 sh = *(const float4*)&As[K + k];
            ha.x = fmaxf(0.f, fmaf(ha.x, sc.x, sh.x));
            ha.y = fmaxf(0.f, fmaf(ha.y, sc.y, sh.y));
            ha.z = fmaxf(0.f, fmaf(ha.z, sc.z, sh.z));
            ha.w = fmaxf(0.f, fmaf(ha.w, sc.w, sh.w));
            hb.x = fmaxf(0.f, fmaf(hb.x, sc.x, sh.x));
            hb.y = fmaxf(0.f, fmaf(hb.y, sc.y, sh.y));
            hb.z = fmaxf(0.f, fmaf(hb.z, sc.z, sh.z));
            hb.w = fmaxf(0.f, fmaf(hb.w, sc.w, sh.w));
        }
        const float hA[4] = { ha.x, ha.y, ha.z, ha.w };
        const float hB[4] = { hb.x, hb.y, hb.z, hb.w };
#pragma unroll
        for (int j = 0; j < 4; ++j) {
            const float4* wr = (const float4*)&Ws[(k + j) * HID + c0];
            const float xa = hA[j], xb = hB[j];
#pragma unroll
            for (int q = 0; q < 4; ++q) {
                const float4 wv = wr[q];
                acc0[q * 4 + 0] = fmaf(xa, wv.x, acc0[q * 4 + 0]);
                acc0[q * 4 + 1] = fmaf(xa, wv.y, acc0[q * 4 + 1]);
                acc0[q * 4 + 2] = fmaf(xa, wv.z, acc0[q * 4 + 2]);
                acc0[q * 4 + 3] = fmaf(xa, wv.w, acc0[q * 4 + 3]);
                acc1[q * 4 + 0] = fmaf(xb, wv.x, acc1[q * 4 + 0]);
                acc1[q * 4 + 1] = fmaf(xb, wv.y, acc1[q * 4 + 1]);
                acc1[q * 4 + 2] = fmaf(xb, wv.z, acc1[q * 4 + 2]);
                acc1[q * 4 + 3] = fmaf(xb, wv.w, acc1[q * 4 + 3]);
            }
        }
    }

    if (v0) {
        const float d = dinv[row];
        uint4 p0, p1;
        p0.x = f2b2(acc0[0] * d,  acc0[1] * d);
        p0.y = f2b2(acc0[2] * d,  acc0[3] * d);
        p0.z = f2b2(acc0[4] * d,  acc0[5] * d);
        p0.w = f2b2(acc0[6] * d,  acc0[7] * d);
        p1.x = f2b2(acc0[8] * d,  acc0[9] * d);
        p1.y = f2b2(acc0[10] * d, acc0[11] * d);
        p1.z = f2b2(acc0[12] * d, acc0[13] * d);
        p1.w = f2b2(acc0[14] * d, acc0[15] * d);
        uint4* dst = (uint4*)&ts[(size_t)row * HID + c0];
        dst[0] = p0; dst[1] = p1;
    }
    if (v1) {
        const float d = dinv[row + 1];
        uint4 p0, p1;
        p0.x = f2b2(acc1[0] * d,  acc1[1] * d);
        p0.y = f2b2(acc1[2] * d,  acc1[3] * d);
        p0.z = f2b2(acc1[4] * d,  acc1[5] * d);
        p0.w = f2b2(acc1[6] * d,  acc1[7] * d);
        p1.x = f2b2(acc1[8] * d,  acc1[9] * d);
        p1.y = f2b2(acc1[10] * d, acc1[11] * d);
        p1.z = f2b2(acc1[12] * d, acc1[13] * d);
        p1.w = f2b2(acc1[14] * d, acc1[15] * d);
        uint4* dst = (uint4*)&ts[(size_t)(row + 1) * HID + c0];
        dst[0] = p0; dst[1] = p1;
    }
}

#define ACC8(r)                                             \
    a0 += u2f_lo(r.x); a1 += u2f_hi(r.x);                   \
    a2 += u2f_lo(r.y); a3 += u2f_hi(r.y);                   \
    a4 += u2f_lo(r.z); a5 += u2f_hi(r.z);                   \
    a6 += u2f_lo(r.w); a7 += u2f_hi(r.w);

// ---------------------------------------------------------------------------
// Chunked CSR gather (bf16 ts) + BN epilogue. 8 nodes/wave, 8-lane groups,
// lane owns 8 features (uint4). Chunk loop outermost: all CUs gather from a
// ~1.6MB L2-resident src window at a time; acc stays in registers.
// ---------------------------------------------------------------------------
__global__ __launch_bounds__(256) void k_gather_bn(const uint4* __restrict__ ts8,
                                                   const int* __restrict__ rp,
                                                   const int* __restrict__ col,
                                                   const float* __restrict__ dinv,
                                                   const float* __restrict__ bias,
                                                   float* __restrict__ y,
                                                   float* __restrict__ stats) {
    const int tid  = threadIdx.x;
    const int w    = tid >> 6;
    const int lane = tid & 63;
    const int grp  = lane >> 3;          // 0..7
    const int sl   = lane & 7;           // 0..7
    const float4 bv0 = ((const float4*)bias)[2 * sl];
    const float4 bv1 = ((const float4*)bias)[2 * sl + 1];
    float s0=0.f,s1=0.f,s2=0.f,s3=0.f,s4=0.f,s5=0.f,s6=0.f,s7=0.f;
    float q0=0.f,q1=0.f,q2=0.f,q3=0.f,q4=0.f,q5=0.f,q6=0.f,q7=0.f;

    for (int oct = blockIdx.x * 4 + w; oct < N_NODES / 8; oct += gridDim.x * 4) {
        const int node = oct * 8 + grp;
        const uint4 self = ts8[(size_t)node * 8 + sl];
        float a0 = u2f_lo(self.x), a1 = u2f_hi(self.x);
        float a2 = u2f_lo(self.y), a3 = u2f_hi(self.y);
        float a4 = u2f_lo(self.z), a5 = u2f_hi(self.z);
        float a6 = u2f_lo(self.w), a7 = u2f_hi(self.w);
        int e = rp[node * NCHUNK];
#pragma unroll 1
        for (int c = 1; c <= NCHUNK; ++c) {
            const int e1 = rp[node * NCHUNK + c];
            for (; e + 3 < e1; e += 4) {
                const int u0 = col[e], u1 = col[e + 1], u2 = col[e + 2], u3 = col[e + 3];
                const uint4 r0 = ts8[(size_t)u0 * 8 + sl];
                const uint4 r1 = ts8[(size_t)u1 * 8 + sl];
                const uint4 r2 = ts8[(size_t)u2 * 8 + sl];
                const uint4 r3 = ts8[(size_t)u3 * 8 + sl];
                ACC8(r0) ACC8(r1) ACC8(r2) ACC8(r3)
            }
            for (; e < e1; ++e) {
                const uint4 r = ts8[(size_t)col[e] * 8 + sl];
                ACC8(r)
            }
        }
        const float d = dinv[node];
        const float v0 = fmaf(a0, d, bv0.x), v1 = fmaf(a1, d, bv0.y);
        const float v2 = fmaf(a2, d, bv0.z), v3 = fmaf(a3, d, bv0.w);
        const float v4 = fmaf(a4, d, bv1.x), v5 = fmaf(a5, d, bv1.y);
        const float v6 = fmaf(a6, d, bv1.z), v7 = fmaf(a7, d, bv1.w);
        float4* yr = (float4*)y + (size_t)node * 16 + 2 * sl;
        yr[0] = make_float4(v0, v1, v2, v3);
        yr[1] = make_float4(v4, v5, v6, v7);
        s0 += v0; q0 += v0 * v0;  s1 += v1; q1 += v1 * v1;
        s2 += v2; q2 += v2 * v2;  s3 += v3; q3 += v3 * v3;
        s4 += v4; q4 += v4 * v4;  s5 += v5; q5 += v5 * v5;
        s6 += v6; q6 += v6 * v6;  s7 += v7; q7 += v7 * v7;
    }

#pragma unroll
    for (int off = 8; off <= 32; off <<= 1) {
        s0 += __shfl_xor(s0, off, 64); q0 += __shfl_xor(q0, off, 64);
        s1 += __shfl_xor(s1, off, 64); q1 += __shfl_xor(q1, off, 64);
        s2 += __shfl_xor(s2, off, 64); q2 += __shfl_xor(q2, off, 64);
        s3 += __shfl_xor(s3, off, 64); q3 += __shfl_xor(q3, off, 64);
        s4 += __shfl_xor(s4, off, 64); q4 += __shfl_xor(q4, off, 64);
        s5 += __shfl_xor(s5, off, 64); q5 += __shfl_xor(q5, off, 64);
        s6 += __shfl_xor(s6, off, 64); q6 += __shfl_xor(q6, off, 64);
        s7 += __shfl_xor(s7, off, 64); q7 += __shfl_xor(q7, off, 64);
    }
    __shared__ float smS[4][64];
    __shared__ float smQ[4][64];
    if (grp == 0) {
        *(float4*)&smS[w][8 * sl]     = make_float4(s0, s1, s2, s3);
        *(float4*)&smS[w][8 * sl + 4] = make_float4(s4, s5, s6, s7);
        *(float4*)&smQ[w][8 * sl]     = make_float4(q0, q1, q2, q3);
        *(float4*)&smQ[w][8 * sl + 4] = make_float4(q4, q5, q6, q7);
    }
    __syncthreads();
    if (tid < 64) {
        float t1 = smS[0][tid] + smS[1][tid] + smS[2][tid] + smS[3][tid];
        float t2 = smQ[0][tid] + smQ[1][tid] + smQ[2][tid] + smQ[3][tid];
        atomicAdd(&stats[tid],      t1);
        atomicAdd(&stats[64 + tid], t2);
    }
}

__global__ void k_bn_final(const float* __restrict__ stats,
                           const float* __restrict__ g,
                           const float* __restrict__ be,
                           float* __restrict__ affine) {
    int c = threadIdx.x;
    if (c < HID) {
        float mu  = stats[c] * (1.0f / N_NODES);
        float var = stats[64 + c] * (1.0f / N_NODES) - mu * mu;
        var = fmaxf(var, 0.f);
        float sc = g[c] * rsqrtf(var + EPS_BN);
        affine[c]       = sc;
        affine[HID + c] = fmaf(-mu, sc, be[c]);
    }
}

// ---------------------------------------------------------------------------
// Chunked CSR gather + final fc
// ---------------------------------------------------------------------------
__global__ __launch_bounds__(256) void k_gather_final(const uint4* __restrict__ ts8,
                                                      const int* __restrict__ rp,
                                                      const int* __restrict__ col,
                                                      const float* __restrict__ dinv,
                                                      const float* __restrict__ b2,
                                                      const float* __restrict__ fcW,
                                                      const float* __restrict__ fcb,
                                                      float* __restrict__ out) {
    const int tid  = threadIdx.x;
    const int w    = tid >> 6;
    const int lane = tid & 63;
    const int grp  = lane >> 3;
    const int sl   = lane & 7;
    const float4 bv0 = ((const float4*)b2)[2 * sl];
    const float4 bv1 = ((const float4*)b2)[2 * sl + 1];
    const float4 fw0 = ((const float4*)fcW)[2 * sl];
    const float4 fw1 = ((const float4*)fcW)[2 * sl + 1];
    const float  fb  = fcb[0];

    for (int oct = blockIdx.x * 4 + w; oct < N_NODES / 8; oct += gridDim.x * 4) {
        const int node = oct * 8 + grp;
        const uint4 self = ts8[(size_t)node * 8 + sl];
        float a0 = u2f_lo(self.x), a1 = u2f_hi(self.x);
        float a2 = u2f_lo(self.y), a3 = u2f_hi(self.y);
        float a4 = u2f_lo(self.z), a5 = u2f_hi(self.z);
        float a6 = u2f_lo(self.w), a7 = u2f_hi(self.w);
        int e = rp[node * NCHUNK];
#pragma unroll 1
        for (int c = 1; c <= NCHUNK; ++c) {
            const int e1 = rp[node * NCHUNK + c];
            for (; e + 3 < e1; e += 4) {
                const int u0 = col[e], u1 = col[e + 1], u2 = col[e + 2], u3 = col[e + 3];
                const uint4 r0 = ts8[(size_t)u0 * 8 + sl];
                const uint4 r1 = ts8[(size_t)u1 * 8 + sl];
                const uint4 r2 = ts8[(size_t)u2 * 8 + sl];
                const uint4 r3 = ts8[(size_t)u3 * 8 + sl];
                ACC8(r0) ACC8(r1) ACC8(r2) ACC8(r3)
            }
            for (; e < e1; ++e) {
                const uint4 r = ts8[(size_t)col[e] * 8 + sl];
                ACC8(r)
            }
        }
        const float d = dinv[node];
        float v = fmaxf(0.f, fmaf(a0, d, bv0.x)) * fw0.x
                + fmaxf(0.f, fmaf(a1, d, bv0.y)) * fw0.y
                + fmaxf(0.f, fmaf(a2, d, bv0.z)) * fw0.z
                + fmaxf(0.f, fmaf(a3, d, bv0.w)) * fw0.w
                + fmaxf(0.f, fmaf(a4, d, bv1.x)) * fw1.x
                + fmaxf(0.f, fmaf(a5, d, bv1.y)) * fw1.y
                + fmaxf(0.f, fmaf(a6, d, bv1.z)) * fw1.z
                + fmaxf(0.f, fmaf(a7, d, bv1.w)) * fw1.w;
#pragma unroll
        for (int off = 4; off >= 1; off >>= 1) v += __shfl_xor(v, off, 64);
        if (sl == 0) out[node] = v + fb;
    }
}

// ---------------------------------------------------------------------------
extern "C" void kernel_launch(void* const* d_in, const int* in_sizes, int n_in,
                              void* d_out, int out_size, void* d_ws, size_t ws_size,
                              hipStream_t stream) {
    const float* x    = (const float*)d_in[0];
    const int*   ei   = (const int*)d_in[1];
    const float* W0   = (const float*)d_in[2];
    const float* b0   = (const float*)d_in[3];
    const float* W1   = (const float*)d_in[4];
    const float* b1   = (const float*)d_in[5];
    const float* W2   = (const float*)d_in[6];
    const float* b2   = (const float*)d_in[7];
    const float* g0   = (const float*)d_in[8];
    const float* be0  = (const float*)d_in[9];
    const float* g1   = (const float*)d_in[10];
    const float* be1  = (const float*)d_in[11];
    const float* fcW  = (const float*)d_in[12];
    const float* fcb  = (const float*)d_in[13];
    float* out        = (float*)d_out;

    char* ws = (char*)d_ws;
    size_t off = 0;
    auto alloc = [&](size_t bytes) -> void* {
        size_t o = off;
        off += (bytes + 255) & ~(size_t)255;
        return (void*)(ws + o);
    };
    unsigned short* ts = (unsigned short*)alloc((size_t)N_NODES * HID * 2);
    float* bufY    = (float*)alloc((size_t)N_NODES * HID * 4);
    int*   col     = (int*)  alloc((size_t)N_EDGES * 4);
    float* dinv    = (float*)alloc((size_t)N_NODES * 4);
    int*   counts  = (int*)  alloc((size_t)NCNT * 4);
    int*   fill    = (int*)  alloc((size_t)NCNT * 4);
    int*   rowptr  = (int*)  alloc((size_t)(NCNT + 1) * 4);
    int*   bsum    = (int*)  alloc((size_t)NBLK1 * 4);
    int*   boff    = (int*)  alloc((size_t)NBLK1 * 4);
    float* stats0  = (float*)alloc(2 * HID * 4);
    float* stats1  = (float*)alloc(2 * HID * 4);
    float* affine0 = (float*)alloc(2 * HID * 4);
    float* affine1 = (float*)alloc(2 * HID * 4);

    const int gN    = (N_NODES + 255) / 256;
    const int gE    = (N_EDGES + 255) / 256;
    const int gGemm = (N_NODES + 127) / 128;
    const int gGath = (N_NODES / 8 + 3) / 4;

    k_zero<<<NBLK1, 256, 0, stream>>>(counts, fill, stats0, stats1);
    k_count<<<gE, 256, 0, stream>>>(ei, counts);
    k_scan1<<<NBLK1, 256, 0, stream>>>(counts, rowptr, bsum);
    k_scan2<<<1, 1024, 0, stream>>>(bsum, boff);
    k_scan3<<<NBLK1, 256, 0, stream>>>(rowptr, boff);
    k_dinv<<<gN, 256, 0, stream>>>(rowptr, dinv);
    k_scatter<<<gE, 256, 0, stream>>>(ei, rowptr, fill, col);

    // ---- layer 0
    k_gemm<NFEAT, false><<<gGemm, 256, 0, stream>>>(x, W0, dinv, nullptr, ts);
    k_gather_bn<<<gGath, 256, 0, stream>>>((const uint4*)ts, rowptr, col, dinv, b0, bufY, stats0);
    k_bn_final<<<1, 64, 0, stream>>>(stats0, g0, be0, affine0);

    // ---- layer 1
    k_gemm<HID, true><<<gGemm, 256, 0, stream>>>(bufY, W1, dinv, affine0, ts);
    k_gather_bn<<<gGath, 256, 0, stream>>>((const uint4*)ts, rowptr, col, dinv, b1, bufY, stats1);
    k_bn_final<<<1, 64, 0, stream>>>(stats1, g1, be1, affine1);

    // ---- layer 2
    k_gemm<HID, true><<<gGemm, 256, 0, stream>>>(bufY, W2, dinv, affine1, ts);
    k_gather_final<<<gGath, 256, 0, stream>>>((const uint4*)ts, rowptr, col, dinv, b2, fcW, fcb, out);
}

// Round 7
// 288.433 us; speedup vs baseline: 2.7463x; 1.1141x over previous
//
#include <hip/hip_runtime.h>

#define N_NODES 50000
#define N_EDGES 800000
#define NFEAT   128
#define HID     64
#define EPS_BN  1e-5f
#define NCHUNK  2
#define CHN     (N_NODES / NCHUNK)          // 25000 src nodes per chunk (~3.2 MB of ts)
#define NCNT    (N_NODES * NCHUNK)          // 100000 (row,chunk) buckets
#define NBLK1   ((NCNT + 255) / 256)        // 391

// bf16 helpers
__device__ __forceinline__ float u2f_lo(unsigned int u) {
    union { unsigned int i; float f; } c; c.i = u << 16; return c.f;
}
__device__ __forceinline__ float u2f_hi(unsigned int u) {
    union { unsigned int i; float f; } c; c.i = u & 0xffff0000u; return c.f;
}
__device__ __forceinline__ unsigned int f2b2(float lo, float hi) {
    union { float f; unsigned int i; } a, b;
    a.f = lo; b.f = hi;
    unsigned int x = (a.i + 0x7fffu + ((a.i >> 16) & 1u)) >> 16;
    unsigned int y = (b.i + 0x7fffu + ((b.i >> 16) & 1u)) & 0xffff0000u;
    return x | y;
}

// ---------------------------------------------------------------------------
// CSR build: (row, src-chunk) buckets, each padded to a multiple of 4 edges
// with sentinel src = N_NODES (a zeroed ts row).
// ---------------------------------------------------------------------------
__global__ void k_zero(int* __restrict__ counts, int* __restrict__ fill,
                       float* __restrict__ st0, float* __restrict__ st1,
                       unsigned short* __restrict__ ts) {
    int i = blockIdx.x * 256 + threadIdx.x;
    if (i < NCNT) { counts[i] = 0; fill[i] = 0; }
    if (i < 2 * HID) { st0[i] = 0.f; st1[i] = 0.f; }
    if (i < 32) ((unsigned int*)(ts + (size_t)N_NODES * HID))[i] = 0u;  // zero row
}

__global__ void k_count(const int* __restrict__ ei, int* __restrict__ counts) {
    int e = blockIdx.x * 256 + threadIdx.x;
    if (e >= N_EDGES) return;
    int s = ei[e];
    int t = ei[N_EDGES + e];
    atomicAdd(&counts[t * NCHUNK + s / CHN], 1);
}

// phase 1: per-block exclusive scan of PADDED counts
__global__ __launch_bounds__(256) void k_scan1(const int* __restrict__ counts,
                                               int* __restrict__ rowptr,
                                               int* __restrict__ bsum) {
    const int tid = threadIdx.x;
    const int i   = blockIdx.x * 256 + tid;
    int v = (i < NCNT) ? ((counts[i] + 3) & ~3) : 0;
    __shared__ int sm[256];
    sm[tid] = v;
    __syncthreads();
    for (int off = 1; off < 256; off <<= 1) {
        int t = (tid >= off) ? sm[tid - off] : 0;
        __syncthreads();
        sm[tid] += t;
        __syncthreads();
    }
    if (i < NCNT) rowptr[i] = sm[tid] - v;
    if (tid == 255) bsum[blockIdx.x] = sm[255];
}

__global__ __launch_bounds__(1024) void k_scan2(const int* __restrict__ bsum,
                                                int* __restrict__ boff,
                                                int* __restrict__ rowptr) {
    const int tid = threadIdx.x;
    int v = (tid < NBLK1) ? bsum[tid] : 0;
    __shared__ int sm[1024];
    sm[tid] = v;
    __syncthreads();
    for (int off = 1; off < 1024; off <<= 1) {
        int t = (tid >= off) ? sm[tid - off] : 0;
        __syncthreads();
        sm[tid] += t;
        __syncthreads();
    }
    if (tid < NBLK1) boff[tid] = sm[tid] - v;
    if (tid == NBLK1 - 1) rowptr[NCNT] = sm[tid];   // total padded edges
}

__global__ __launch_bounds__(256) void k_scan3(int* __restrict__ rowptr,
                                               const int* __restrict__ boff) {
    const int i = blockIdx.x * 256 + threadIdx.x;
    if (i < NCNT) rowptr[i] += boff[blockIdx.x];
}

__global__ void k_dinv(const int* __restrict__ counts, float* __restrict__ dinv) {
    int i = blockIdx.x * 256 + threadIdx.x;
    if (i < N_NODES) {
        int deg = 1;
#pragma unroll
        for (int c = 0; c < NCHUNK; ++c) deg += counts[i * NCHUNK + c];
        dinv[i] = rsqrtf((float)deg);
    }
}

__global__ void k_scatter(const int* __restrict__ ei, const int* __restrict__ rowptr,
                          int* __restrict__ fill, int* __restrict__ col) {
    int e = blockIdx.x * 256 + threadIdx.x;
    if (e >= N_EDGES) return;
    int s = ei[e];
    int t = ei[N_EDGES + e];
    int b = t * NCHUNK + s / CHN;
    int pos = rowptr[b] + atomicAdd(&fill[b], 1);
    col[pos] = s;
}

// fill pad slots with sentinel (zero row)
__global__ void k_pad(const int* __restrict__ counts, const int* __restrict__ rowptr,
                      int* __restrict__ col) {
    int b = blockIdx.x * 256 + threadIdx.x;
    if (b >= NCNT) return;
    int cnt = counts[b];
    int start = rowptr[b] + cnt;
    int end   = rowptr[b] + ((cnt + 3) & ~3);
    for (int p = start; p < end; ++p) col[p] = N_NODES;
}

// ---------------------------------------------------------------------------
// GEMM: ts[row][col] = bf16( dinv[row] * sum_k Hin[row][k] * W[k][col] )
// W-only LDS staging; thread = 2 rows x 16 cols register tile.
// ---------------------------------------------------------------------------
template <int K, bool AFFINE>
__global__ __launch_bounds__(256) void k_gemm(const float* __restrict__ H,
                                              const float* __restrict__ W,
                                              const float* __restrict__ dinv,
                                              const float* __restrict__ affine,
                                              unsigned short* __restrict__ ts) {
    __shared__ float Ws[K * HID];
    __shared__ float As[2 * K];
    const int tid = threadIdx.x;
    for (int i = tid * 4; i < K * HID; i += 256 * 4)
        *(float4*)&Ws[i] = *(const float4*)&W[i];
    if (AFFINE) {
        if (tid < (2 * K) / 4)
            *(float4*)&As[tid * 4] = *(const float4*)&affine[tid * 4];
    }
    __syncthreads();

    const int quad = tid & 3;
    const int rp_  = tid >> 2;
    const int row  = blockIdx.x * 128 + rp_ * 2;
    const int c0   = quad * 16;
    const bool v0  = row < N_NODES;
    const bool v1  = row + 1 < N_NODES;

    float acc0[16], acc1[16];
#pragma unroll
    for (int i = 0; i < 16; ++i) { acc0[i] = 0.f; acc1[i] = 0.f; }

    const float* h0p = H + (size_t)row * K;
    const float4 z4 = make_float4(0.f, 0.f, 0.f, 0.f);

#pragma unroll 2
    for (int k = 0; k < K; k += 4) {
        float4 ha = v0 ? *(const float4*)(h0p + k) : z4;
        float4 hb = v1 ? *(const float4*)(h0p + K + k) : z4;
        if (AFFINE) {
            const float4 sc = *(const float4*)&As[k];
            const float4 sh = *(const float4*)&As[K + k];
            ha.x = fmaxf(0.f, fmaf(ha.x, sc.x, sh.x));
            ha.y = fmaxf(0.f, fmaf(ha.y, sc.y, sh.y));
            ha.z = fmaxf(0.f, fmaf(ha.z, sc.z, sh.z));
            ha.w = fmaxf(0.f, fmaf(ha.w, sc.w, sh.w));
            hb.x = fmaxf(0.f, fmaf(hb.x, sc.x, sh.x));
            hb.y = fmaxf(0.f, fmaf(hb.y, sc.y, sh.y));
            hb.z = fmaxf(0.f, fmaf(hb.z, sc.z, sh.z));
            hb.w = fmaxf(0.f, fmaf(hb.w, sc.w, sh.w));
        }
        const float hA[4] = { ha.x, ha.y, ha.z, ha.w };
        const float hB[4] = { hb.x, hb.y, hb.z, hb.w };
#pragma unroll
        for (int j = 0; j < 4; ++j) {
            const float4* wr = (const float4*)&Ws[(k + j) * HID + c0];
            const float xa = hA[j], xb = hB[j];
#pragma unroll
            for (int q = 0; q < 4; ++q) {
                const float4 wv = wr[q];
                acc0[q * 4 + 0] = fmaf(xa, wv.x, acc0[q * 4 + 0]);
                acc0[q * 4 + 1] = fmaf(xa, wv.y, acc0[q * 4 + 1]);
                acc0[q * 4 + 2] = fmaf(xa, wv.z, acc0[q * 4 + 2]);
                acc0[q * 4 + 3] = fmaf(xa, wv.w, acc0[q * 4 + 3]);
                acc1[q * 4 + 0] = fmaf(xb, wv.x, acc1[q * 4 + 0]);
                acc1[q * 4 + 1] = fmaf(xb, wv.y, acc1[q * 4 + 1]);
                acc1[q * 4 + 2] = fmaf(xb, wv.z, acc1[q * 4 + 2]);
                acc1[q * 4 + 3] = fmaf(xb, wv.w, acc1[q * 4 + 3]);
            }
        }
    }

    if (v0) {
        const float d = dinv[row];
        uint4 p0, p1;
        p0.x = f2b2(acc0[0] * d,  acc0[1] * d);
        p0.y = f2b2(acc0[2] * d,  acc0[3] * d);
        p0.z = f2b2(acc0[4] * d,  acc0[5] * d);
        p0.w = f2b2(acc0[6] * d,  acc0[7] * d);
        p1.x = f2b2(acc0[8] * d,  acc0[9] * d);
        p1.y = f2b2(acc0[10] * d, acc0[11] * d);
        p1.z = f2b2(acc0[12] * d, acc0[13] * d);
        p1.w = f2b2(acc0[14] * d, acc0[15] * d);
        uint4* dst = (uint4*)&ts[(size_t)row * HID + c0];
        dst[0] = p0; dst[1] = p1;
    }
    if (v1) {
        const float d = dinv[row + 1];
        uint4 p0, p1;
        p0.x = f2b2(acc1[0] * d,  acc1[1] * d);
        p0.y = f2b2(acc1[2] * d,  acc1[3] * d);
        p0.z = f2b2(acc1[4] * d,  acc1[5] * d);
        p0.w = f2b2(acc1[6] * d,  acc1[7] * d);
        p1.x = f2b2(acc1[8] * d,  acc1[9] * d);
        p1.y = f2b2(acc1[10] * d, acc1[11] * d);
        p1.z = f2b2(acc1[12] * d, acc1[13] * d);
        p1.w = f2b2(acc1[14] * d, acc1[15] * d);
        uint4* dst = (uint4*)&ts[(size_t)(row + 1) * HID + c0];
        dst[0] = p0; dst[1] = p1;
    }
}

#define ACC8(r)                                             \
    a0 += u2f_lo(r.x); a1 += u2f_hi(r.x);                   \
    a2 += u2f_lo(r.y); a3 += u2f_hi(r.y);                   \
    a4 += u2f_lo(r.z); a5 += u2f_hi(r.z);                   \
    a6 += u2f_lo(r.w); a7 += u2f_hi(r.w);

// ---------------------------------------------------------------------------
// Padded CSR gather (bf16 ts) + BN epilogue. 8 nodes/wave, 8-lane groups,
// lane owns 8 features (uint4). Single uniform loop per node (buckets padded
// to x4, contiguous per node => chunk phasing preserved); col via int4.
// ---------------------------------------------------------------------------
__global__ __launch_bounds__(256) void k_gather_bn(const uint4* __restrict__ ts8,
                                                   const int* __restrict__ rp,
                                                   const int* __restrict__ col,
                                                   const float* __restrict__ dinv,
                                                   const float* __restrict__ bias,
                                                   float* __restrict__ y,
                                                   float* __restrict__ stats) {
    const int tid  = threadIdx.x;
    const int w    = tid >> 6;
    const int lane = tid & 63;
    const int grp  = lane >> 3;          // 0..7
    const int sl   = lane & 7;           // 0..7
    const float4 bv0 = ((const float4*)bias)[2 * sl];
    const float4 bv1 = ((const float4*)bias)[2 * sl + 1];
    float s0=0.f,s1=0.f,s2=0.f,s3=0.f,s4=0.f,s5=0.f,s6=0.f,s7=0.f;
    float q0=0.f,q1=0.f,q2=0.f,q3=0.f,q4=0.f,q5=0.f,q6=0.f,q7=0.f;

    for (int oct = blockIdx.x * 4 + w; oct < N_NODES / 8; oct += gridDim.x * 4) {
        const int node = oct * 8 + grp;
        const uint4 self = ts8[(size_t)node * 8 + sl];
        float a0 = u2f_lo(self.x), a1 = u2f_hi(self.x);
        float a2 = u2f_lo(self.y), a3 = u2f_hi(self.y);
        float a4 = u2f_lo(self.z), a5 = u2f_hi(self.z);
        float a6 = u2f_lo(self.w), a7 = u2f_hi(self.w);
        int e        = rp[node * NCHUNK];
        const int e1 = rp[node * NCHUNK + NCHUNK];
        for (; e < e1; e += 4) {
            const int4 cc = *(const int4*)&col[e];
            const uint4 r0 = ts8[(size_t)cc.x * 8 + sl];
            const uint4 r1 = ts8[(size_t)cc.y * 8 + sl];
            const uint4 r2 = ts8[(size_t)cc.z * 8 + sl];
            const uint4 r3 = ts8[(size_t)cc.w * 8 + sl];
            ACC8(r0) ACC8(r1) ACC8(r2) ACC8(r3)
        }
        const float d = dinv[node];
        const float v0 = fmaf(a0, d, bv0.x), v1 = fmaf(a1, d, bv0.y);
        const float v2 = fmaf(a2, d, bv0.z), v3 = fmaf(a3, d, bv0.w);
        const float v4 = fmaf(a4, d, bv1.x), v5 = fmaf(a5, d, bv1.y);
        const float v6 = fmaf(a6, d, bv1.z), v7 = fmaf(a7, d, bv1.w);
        float4* yr = (float4*)y + (size_t)node * 16 + 2 * sl;
        yr[0] = make_float4(v0, v1, v2, v3);
        yr[1] = make_float4(v4, v5, v6, v7);
        s0 += v0; q0 += v0 * v0;  s1 += v1; q1 += v1 * v1;
        s2 += v2; q2 += v2 * v2;  s3 += v3; q3 += v3 * v3;
        s4 += v4; q4 += v4 * v4;  s5 += v5; q5 += v5 * v5;
        s6 += v6; q6 += v6 * v6;  s7 += v7; q7 += v7 * v7;
    }

#pragma unroll
    for (int off = 8; off <= 32; off <<= 1) {
        s0 += __shfl_xor(s0, off, 64); q0 += __shfl_xor(q0, off, 64);
        s1 += __shfl_xor(s1, off, 64); q1 += __shfl_xor(q1, off, 64);
        s2 += __shfl_xor(s2, off, 64); q2 += __shfl_xor(q2, off, 64);
        s3 += __shfl_xor(s3, off, 64); q3 += __shfl_xor(q3, off, 64);
        s4 += __shfl_xor(s4, off, 64); q4 += __shfl_xor(q4, off, 64);
        s5 += __shfl_xor(s5, off, 64); q5 += __shfl_xor(q5, off, 64);
        s6 += __shfl_xor(s6, off, 64); q6 += __shfl_xor(q6, off, 64);
        s7 += __shfl_xor(s7, off, 64); q7 += __shfl_xor(q7, off, 64);
    }
    __shared__ float smS[4][64];
    __shared__ float smQ[4][64];
    if (grp == 0) {
        *(float4*)&smS[w][8 * sl]     = make_float4(s0, s1, s2, s3);
        *(float4*)&smS[w][8 * sl + 4] = make_float4(s4, s5, s6, s7);
        *(float4*)&smQ[w][8 * sl]     = make_float4(q0, q1, q2, q3);
        *(float4*)&smQ[w][8 * sl + 4] = make_float4(q4, q5, q6, q7);
    }
    __syncthreads();
    if (tid < 64) {
        float t1 = smS[0][tid] + smS[1][tid] + smS[2][tid] + smS[3][tid];
        float t2 = smQ[0][tid] + smQ[1][tid] + smQ[2][tid] + smQ[3][tid];
        atomicAdd(&stats[tid],      t1);
        atomicAdd(&stats[64 + tid], t2);
    }
}

__global__ void k_bn_final(const float* __restrict__ stats,
                           const float* __restrict__ g,
                           const float* __restrict__ be,
                           float* __restrict__ affine) {
    int c = threadIdx.x;
    if (c < HID) {
        float mu  = stats[c] * (1.0f / N_NODES);
        float var = stats[64 + c] * (1.0f / N_NODES) - mu * mu;
        var = fmaxf(var, 0.f);
        float sc = g[c] * rsqrtf(var + EPS_BN);
        affine[c]       = sc;
        affine[HID + c] = fmaf(-mu, sc, be[c]);
    }
}

// ---------------------------------------------------------------------------
// Padded CSR gather + final fc
// ---------------------------------------------------------------------------
__global__ __launch_bounds__(256) void k_gather_final(const uint4* __restrict__ ts8,
                                                      const int* __restrict__ rp,
                                                      const int* __restrict__ col,
                                                      const float* __restrict__ dinv,
                                                      const float* __restrict__ b2,
                                                      const float* __restrict__ fcW,
                                                      const float* __restrict__ fcb,
                                                      float* __restrict__ out) {
    const int tid  = threadIdx.x;
    const int w    = tid >> 6;
    const int lane = tid & 63;
    const int grp  = lane >> 3;
    const int sl   = lane & 7;
    const float4 bv0 = ((const float4*)b2)[2 * sl];
    const float4 bv1 = ((const float4*)b2)[2 * sl + 1];
    const float4 fw0 = ((const float4*)fcW)[2 * sl];
    const float4 fw1 = ((const float4*)fcW)[2 * sl + 1];
    const float  fb  = fcb[0];

    for (int oct = blockIdx.x * 4 + w; oct < N_NODES / 8; oct += gridDim.x * 4) {
        const int node = oct * 8 + grp;
        const uint4 self = ts8[(size_t)node * 8 + sl];
        float a0 = u2f_lo(self.x), a1 = u2f_hi(self.x);
        float a2 = u2f_lo(self.y), a3 = u2f_hi(self.y);
        float a4 = u2f_lo(self.z), a5 = u2f_hi(self.z);
        float a6 = u2f_lo(self.w), a7 = u2f_hi(self.w);
        int e        = rp[node * NCHUNK];
        const int e1 = rp[node * NCHUNK + NCHUNK];
        for (; e < e1; e += 4) {
            const int4 cc = *(const int4*)&col[e];
            const uint4 r0 = ts8[(size_t)cc.x * 8 + sl];
            const uint4 r1 = ts8[(size_t)cc.y * 8 + sl];
            const uint4 r2 = ts8[(size_t)cc.z * 8 + sl];
            const uint4 r3 = ts8[(size_t)cc.w * 8 + sl];
            ACC8(r0) ACC8(r1) ACC8(r2) ACC8(r3)
        }
        const float d = dinv[node];
        float v = fmaxf(0.f, fmaf(a0, d, bv0.x)) * fw0.x
                + fmaxf(0.f, fmaf(a1, d, bv0.y)) * fw0.y
                + fmaxf(0.f, fmaf(a2, d, bv0.z)) * fw0.z
                + fmaxf(0.f, fmaf(a3, d, bv0.w)) * fw0.w
                + fmaxf(0.f, fmaf(a4, d, bv1.x)) * fw1.x
                + fmaxf(0.f, fmaf(a5, d, bv1.y)) * fw1.y
                + fmaxf(0.f, fmaf(a6, d, bv1.z)) * fw1.z
                + fmaxf(0.f, fmaf(a7, d, bv1.w)) * fw1.w;
#pragma unroll
        for (int off = 4; off >= 1; off >>= 1) v += __shfl_xor(v, off, 64);
        if (sl == 0) out[node] = v + fb;
    }
}

// ---------------------------------------------------------------------------
extern "C" void kernel_launch(void* const* d_in, const int* in_sizes, int n_in,
                              void* d_out, int out_size, void* d_ws, size_t ws_size,
                              hipStream_t stream) {
    const float* x    = (const float*)d_in[0];
    const int*   ei   = (const int*)d_in[1];
    const float* W0   = (const float*)d_in[2];
    const float* b0   = (const float*)d_in[3];
    const float* W1   = (const float*)d_in[4];
    const float* b1   = (const float*)d_in[5];
    const float* W2   = (const float*)d_in[6];
    const float* b2   = (const float*)d_in[7];
    const float* g0   = (const float*)d_in[8];
    const float* be0  = (const float*)d_in[9];
    const float* g1   = (const float*)d_in[10];
    const float* be1  = (const float*)d_in[11];
    const float* fcW  = (const float*)d_in[12];
    const float* fcb  = (const float*)d_in[13];
    float* out        = (float*)d_out;

    char* ws = (char*)d_ws;
    size_t off = 0;
    auto alloc = [&](size_t bytes) -> void* {
        size_t o = off;
        off += (bytes + 255) & ~(size_t)255;
        return (void*)(ws + o);
    };
    unsigned short* ts = (unsigned short*)alloc((size_t)(N_NODES + 1) * HID * 2);
    float* bufY    = (float*)alloc((size_t)N_NODES * HID * 4);
    int*   col     = (int*)  alloc((size_t)(N_EDGES + 3 * NCNT) * 4);
    float* dinv    = (float*)alloc((size_t)N_NODES * 4);
    int*   counts  = (int*)  alloc((size_t)NCNT * 4);
    int*   fill    = (int*)  alloc((size_t)NCNT * 4);
    int*   rowptr  = (int*)  alloc((size_t)(NCNT + 1) * 4);
    int*   bsum    = (int*)  alloc((size_t)NBLK1 * 4);
    int*   boff    = (int*)  alloc((size_t)NBLK1 * 4);
    float* stats0  = (float*)alloc(2 * HID * 4);
    float* stats1  = (float*)alloc(2 * HID * 4);
    float* affine0 = (float*)alloc(2 * HID * 4);
    float* affine1 = (float*)alloc(2 * HID * 4);

    const int gN    = (N_NODES + 255) / 256;
    const int gE    = (N_EDGES + 255) / 256;
    const int gGemm = (N_NODES + 127) / 128;
    const int gGath = (N_NODES / 8 + 3) / 4;

    k_zero<<<NBLK1, 256, 0, stream>>>(counts, fill, stats0, stats1, ts);
    k_count<<<gE, 256, 0, stream>>>(ei, counts);
    k_scan1<<<NBLK1, 256, 0, stream>>>(counts, rowptr, bsum);
    k_scan2<<<1, 1024, 0, stream>>>(bsum, boff, rowptr);
    k_scan3<<<NBLK1, 256, 0, stream>>>(rowptr, boff);
    k_dinv<<<gN, 256, 0, stream>>>(counts, dinv);
    k_scatter<<<gE, 256, 0, stream>>>(ei, rowptr, fill, col);
    k_pad<<<NBLK1, 256, 0, stream>>>(counts, rowptr, col);

    // ---- layer 0
    k_gemm<NFEAT, false><<<gGemm, 256, 0, stream>>>(x, W0, dinv, nullptr, ts);
    k_gather_bn<<<gGath, 256, 0, stream>>>((const uint4*)ts, rowptr, col, dinv, b0, bufY, stats0);
    k_bn_final<<<1, 64, 0, stream>>>(stats0, g0, be0, affine0);

    // ---- layer 1
    k_gemm<HID, true><<<gGemm, 256, 0, stream>>>(bufY, W1, dinv, affine0, ts);
    k_gather_bn<<<gGath, 256, 0, stream>>>((const uint4*)ts, rowptr, col, dinv, b1, bufY, stats1);
    k_bn_final<<<1, 64, 0, stream>>>(stats1, g1, be1, affine1);

    // ---- layer 2
    k_gemm<HID, true><<<gGemm, 256, 0, stream>>>(bufY, W2, dinv, affine1, ts);
    k_gather_final<<<gGath, 256, 0, stream>>>((const uint4*)ts, rowptr, col, dinv, b2, fcW, fcb, out);
}